// Round 1
// baseline (1759.520 us; speedup 1.0000x reference)
//
#include <hip/hip_runtime.h>
#include <hip/hip_fp16.h>

#define NB 64
#define NSP 784
#define CDIM 512
#define CQK 256
#define C4 128
#define NHEADS 8
#define CCAT 1024
#define BN_EPS 1e-5f
#define ATT_SCALE 0.17677669529663687f  // 32^-0.5

__device__ __forceinline__ void bn_coef(const float* bn, int cout, int o, float& inv, float& add) {
    float g = bn[o], be = bn[cout + o], m = bn[2 * cout + o], v = bn[3 * cout + o];
    inv = g * rsqrtf(v + BN_EPS);
    add = be - m * inv;
}

// Out[b][o][n] = BN(sum_c W[o][c] * In[b][c][n]). Tiles: 128 (o) x 128 (n), BK=8, 8x8 microtile.
// Global column space = NB*NSP = 50176 = 392 tiles of 128 exactly.
template<int CIN, bool IN_HALF, bool OUT_HALF>
__global__ __launch_bounds__(256)
void gemm_bn_kernel(const void* __restrict__ in_v, const float* __restrict__ wg,
                    const float* __restrict__ bn, void* __restrict__ out_v,
                    int cout, int in_bstride, int out_bstride)
{
    const float*  inF = (const float*)in_v;
    const __half* inH = (const __half*)in_v;
    float*  outF = (float*)out_v;
    __half* outH = (__half*)out_v;

    __shared__ float As[8][128];  // [k][col]
    __shared__ float Ws[8][128];  // [k][row(o)]

    const int tid = threadIdx.x;
    const int tx = tid & 15, ty = tid >> 4;
    const int colBase = blockIdx.x * 128;
    const int oBase = blockIdx.y * 128;

    // A staging: thread loads 4 consecutive columns of one k-row.
    // 4-col group starts at multiple of 4; 784 % 4 == 0 so it never crosses a batch boundary.
    const int a_col = (tid & 31) * 4;
    const int a_row = tid >> 5;
    const int gcol_a = colBase + a_col;
    const int b_a = gcol_a / NSP;
    const long a_off = (long)b_a * in_bstride + (gcol_a - b_a * NSP);

    // W staging: thread loads 4 consecutive k of one o-row.
    const int w_row = tid >> 1;
    const int w_col = (tid & 1) * 4;
    const long w_off = (long)(oBase + w_row) * CIN + w_col;

    float acc[8][8];
#pragma unroll
    for (int i = 0; i < 8; ++i)
#pragma unroll
        for (int j = 0; j < 8; ++j) acc[i][j] = 0.f;

    for (int k0 = 0; k0 < CIN; k0 += 8) {
        if constexpr (IN_HALF) {
            union { ushort4 u; __half h[4]; } la;
            la.u = *(const ushort4*)(inH + a_off + (long)(k0 + a_row) * NSP);
#pragma unroll
            for (int q = 0; q < 4; ++q) As[a_row][a_col + q] = __half2float(la.h[q]);
        } else {
            const float4 va = *(const float4*)(inF + a_off + (long)(k0 + a_row) * NSP);
            As[a_row][a_col + 0] = va.x; As[a_row][a_col + 1] = va.y;
            As[a_row][a_col + 2] = va.z; As[a_row][a_col + 3] = va.w;
        }
        const float4 vw = *(const float4*)(wg + w_off + k0);
        Ws[w_col + 0][w_row] = vw.x; Ws[w_col + 1][w_row] = vw.y;
        Ws[w_col + 2][w_row] = vw.z; Ws[w_col + 3][w_row] = vw.w;
        __syncthreads();
#pragma unroll
        for (int kk = 0; kk < 8; ++kk) {
            float a[8], bb[8];
#pragma unroll
            for (int i = 0; i < 4; ++i) { a[i] = Ws[kk][ty * 4 + i]; a[i + 4] = Ws[kk][64 + ty * 4 + i]; }
#pragma unroll
            for (int j = 0; j < 4; ++j) { bb[j] = As[kk][tx * 4 + j]; bb[j + 4] = As[kk][64 + tx * 4 + j]; }
#pragma unroll
            for (int i = 0; i < 8; ++i)
#pragma unroll
                for (int j = 0; j < 8; ++j) acc[i][j] += a[i] * bb[j];
        }
        __syncthreads();
    }

    const int c0 = colBase + tx * 4;
    const int c1 = c0 + 64;
    const int b0 = c0 / NSP, sp0 = c0 - b0 * NSP;
    const int b1 = c1 / NSP, sp1 = c1 - b1 * NSP;

#pragma unroll
    for (int i = 0; i < 8; ++i) {
        const int row = (i < 4) ? (ty * 4 + i) : (64 + ty * 4 + i - 4);
        const int o = oBase + row;
        float inv, add;
        bn_coef(bn, cout, o, inv, add);
        float r[8];
#pragma unroll
        for (int j = 0; j < 8; ++j) r[j] = acc[i][j] * inv + add;
        const long off0 = (long)b0 * out_bstride + (long)o * NSP + sp0;
        const long off1 = (long)b1 * out_bstride + (long)o * NSP + sp1;
        if constexpr (OUT_HALF) {
            union { ushort4 u; __half h[4]; } s0, s1;
#pragma unroll
            for (int q = 0; q < 4; ++q) { s0.h[q] = __float2half(r[q]); s1.h[q] = __float2half(r[4 + q]); }
            *(ushort4*)(outH + off0) = s0.u;
            *(ushort4*)(outH + off1) = s1.u;
        } else {
            *(float4*)(outF + off0) = make_float4(r[0], r[1], r[2], r[3]);
            *(float4*)(outF + off1) = make_float4(r[4], r[5], r[6], r[7]);
        }
    }
}

// Depthwise 5x5 SAME conv + BN on q channels (feat channels 0..127).
__global__ __launch_bounds__(256)
void dwconv_kernel(const float* __restrict__ feat, const float* __restrict__ dww,
                   const float* __restrict__ dwbn, float* __restrict__ qdw)
{
    const int c = blockIdx.x, b = blockIdx.y;
    __shared__ float plane[NSP];
    __shared__ float wsh[25];
    const float* src = feat + ((long)b * CQK + c) * NSP;
    for (int sp = threadIdx.x; sp < NSP; sp += 256) plane[sp] = src[sp];
    if (threadIdx.x < 25) wsh[threadIdx.x] = dww[c * 25 + threadIdx.x];
    __syncthreads();
    float inv, add;
    bn_coef(dwbn, C4, c, inv, add);
    float* dst = qdw + ((long)b * C4 + c) * NSP;
    for (int sp = threadIdx.x; sp < NSP; sp += 256) {
        const int h = sp / 28, w = sp - h * 28;
        float acc = 0.f;
#pragma unroll
        for (int dy = 0; dy < 5; ++dy) {
            const int ih = h + dy - 2;
            if (ih < 0 || ih >= 28) continue;
#pragma unroll
            for (int dx = 0; dx < 5; ++dx) {
                const int iw = w + dx - 2;
                if (iw < 0 || iw >= 28) continue;
                acc += wsh[dy * 5 + dx] * plane[ih * 28 + iw];
            }
        }
        dst[sp] = acc * inv + add;
    }
}

// ROWMODE: fixed h=blockIdx.x, positions are w (attn_w, bias_w).
// COLMODE: fixed w=blockIdx.x, positions are h (attn_h, bias_h).
template<bool ROWMODE>
__global__ __launch_bounds__(256)
void attn_map_kernel(const float* __restrict__ qdw, const float* __restrict__ feat,
                     const float* __restrict__ biasv, const int* __restrict__ bidx,
                     float* __restrict__ attn_out)
{
    const int fix = blockIdx.x, b = blockIdx.y;
    __shared__ float Qs[28][132];
    __shared__ float Ks[28][132];
    __shared__ float S[28][28];
    const float* qbase = qdw + (long)b * C4 * NSP;
    const float* kbase = feat + ((long)b * CQK + C4) * NSP;
    for (int l = threadIdx.x; l < 28 * C4; l += 256) {
        const int c = l / 28;
        const int p = l - c * 28;
        const int sp = ROWMODE ? (fix * 28 + p) : (p * 28 + fix);
        Qs[p][c] = qbase[c * NSP + sp];
        Ks[p][c] = kbase[c * NSP + sp];
    }
    __syncthreads();
    for (int e = threadIdx.x; e < 784; e += 256) {
        const int qp = e / 28, kp = e - (e / 28) * 28;
        float acc = 0.f;
#pragma unroll 8
        for (int c = 0; c < C4; ++c) acc += Qs[qp][c] * Ks[kp][c];
        S[qp][kp] = acc * ATT_SCALE + biasv[bidx[e]];
    }
    __syncthreads();
    if (threadIdx.x < 28) {
        const int r = threadIdx.x;
        float mx = -1e30f;
        for (int k = 0; k < 28; ++k) mx = fmaxf(mx, S[r][k]);
        float sum = 0.f;
        for (int k = 0; k < 28; ++k) { float e2 = __expf(S[r][k] - mx); S[r][k] = e2; sum += e2; }
        const float rinv = 1.f / sum;
        float* dst = attn_out + (((long)b * 28 + fix) * 28 + r) * 28;
        for (int k = 0; k < 28; ++k) dst[k] = S[r][k] * rinv;
    }
}

// casc = (head==0) ? x_slice0 : casc + x_slice_head
__global__ __launch_bounds__(256)
void casc_update_kernel(const float* __restrict__ x, float* __restrict__ casc, int head)
{
    const int i4 = blockIdx.x * 256 + threadIdx.x;
    const long e = (long)i4 * 4;
    const int b = (int)(e / (64 * NSP));
    const int r = (int)(e - (long)b * 64 * NSP);
    const float4 xv = *(const float4*)(x + (long)b * CDIM * NSP + (long)head * 64 * NSP + r);
    float4* cp = (float4*)(casc + e);
    if (head == 0) { *cp = xv; }
    else { float4 c = *cp; c.x += xv.x; c.y += xv.y; c.z += xv.z; c.w += xv.w; *cp = c; }
}

// Row attention, in place on the head's concat slice. Block = (k-row, b).
// M1[d,k,w] = sum_j attn_w[b,k,w,j] * V[d,k,j]
__global__ __launch_bounds__(256)
void stage1_kernel(__half* __restrict__ concat, const float* __restrict__ attnw, int head)
{
    const int k = blockIdx.x, b = blockIdx.y;
    __shared__ float V[128][28];
    __shared__ float A[784];
    __half* ptr = concat + ((long)b * CCAT + head * C4) * NSP + k * 28;
    for (int l = threadIdx.x; l < 128 * 28; l += 256) {
        const int d = l / 28, j = l - (l / 28) * 28;
        V[d][j] = __half2float(ptr[(long)d * NSP + j]);
    }
    for (int l = threadIdx.x; l < 784; l += 256)
        A[l] = attnw[(((long)b * 28) + k) * 784 + l];
    __syncthreads();
    for (int l = threadIdx.x; l < 128 * 28; l += 256) {
        const int d = l / 28, w = l - (l / 28) * 28;
        float acc = 0.f;
#pragma unroll
        for (int j = 0; j < 28; ++j) acc += A[w * 28 + j] * V[d][j];
        ptr[(long)d * NSP + w] = __float2half(acc);
    }
}

// Column attention + ReLU, in place. Block = (w-column, b).
// out[d,h,w] = relu(sum_k attn_h[b,w,h,k] * M1[d,k,w])
__global__ __launch_bounds__(256)
void stage2_kernel(__half* __restrict__ concat, const float* __restrict__ attnh, int head)
{
    const int w = blockIdx.x, b = blockIdx.y;
    __shared__ float M[128][28];
    __shared__ float A[784];
    __half* ptr = concat + ((long)b * CCAT + head * C4) * NSP + w;
    for (int l = threadIdx.x; l < 128 * 28; l += 256) {
        const int d = l / 28, kk = l - (l / 28) * 28;
        M[d][kk] = __half2float(ptr[(long)d * NSP + kk * 28]);
    }
    for (int l = threadIdx.x; l < 784; l += 256)
        A[l] = attnh[(((long)b * 28) + w) * 784 + l];
    __syncthreads();
    for (int l = threadIdx.x; l < 128 * 28; l += 256) {
        const int d = l / 28, h = l - (l / 28) * 28;
        float acc = 0.f;
#pragma unroll
        for (int kk = 0; kk < 28; ++kk) acc += A[h * 28 + kk] * M[d][kk];
        ptr[(long)d * NSP + h * 28] = __float2half(fmaxf(acc, 0.f));
    }
}

extern "C" void kernel_launch(void* const* d_in, const int* in_sizes, int n_in,
                              void* d_out, int out_size, void* d_ws, size_t ws_size,
                              hipStream_t stream)
{
    const float* x        = (const float*)d_in[0];
    const float* qk_w     = (const float*)d_in[1];
    const float* qk_bn    = (const float*)d_in[2];
    const float* dws_w    = (const float*)d_in[3];
    const float* dws_bn   = (const float*)d_in[4];
    const float* vs_w     = (const float*)d_in[5];
    const float* vs_bn    = (const float*)d_in[6];
    const float* proj_w   = (const float*)d_in[7];
    const float* proj_bn  = (const float*)d_in[8];
    const float* bias_h   = (const float*)d_in[9];
    const float* bias_w   = (const float*)d_in[10];
    const int*   bias_idx = (const int*)d_in[11];
    float* out = (float*)d_out;

    char* ws = (char*)d_ws;
    // Region A (102,760,448 B): concat f16 [64][1024][784]; feat/qdw alias it (dead before concat written).
    __half* concat = (__half*)ws;
    float*  feat   = (float*)ws;                                  // [64][256][784] f32
    float*  qdw    = (float*)(ws + (size_t)NB * CQK * NSP * 4);   // [64][128][784] f32
    float*  attw   = (float*)(ws + (size_t)NB * CCAT * NSP * 2);  // [64][28][28][28] f32
    float*  atth   = attw + (size_t)NB * 28 * 784;
    float*  casc   = atth + (size_t)NB * 28 * 784;                // [64][64][784] f32

    // 1. feat = BN(qk_w @ x)
    gemm_bn_kernel<CDIM, false, false><<<dim3(392, 2), 256, 0, stream>>>(
        x, qk_w, qk_bn, feat, CQK, CDIM * NSP, CQK * NSP);
    // 2. q_dw = BN(depthwise5x5(q))
    dwconv_kernel<<<dim3(C4, NB), 256, 0, stream>>>(feat, dws_w, dws_bn, qdw);
    // 3/4. attention maps
    attn_map_kernel<true><<<dim3(28, NB), 256, 0, stream>>>(qdw, feat, bias_w, bias_idx, attw);
    attn_map_kernel<false><<<dim3(28, NB), 256, 0, stream>>>(qdw, feat, bias_h, bias_idx, atth);

    // 5. cascaded heads
    for (int head = 0; head < NHEADS; ++head) {
        casc_update_kernel<<<3136, 256, 0, stream>>>(x, casc, head);
        gemm_bn_kernel<64, false, true><<<dim3(392, 1), 256, 0, stream>>>(
            casc, vs_w + head * C4 * 64, vs_bn + head * 4 * C4,
            concat + (size_t)head * C4 * NSP, C4, 64 * NSP, CCAT * NSP);
        stage1_kernel<<<dim3(28, NB), 256, 0, stream>>>(concat, attw, head);
        stage2_kernel<<<dim3(28, NB), 256, 0, stream>>>(concat, atth, head);
    }

    // 6. out = BN(proj_w @ relu(concat))
    gemm_bn_kernel<CCAT, true, false><<<dim3(392, 4), 256, 0, stream>>>(
        concat, proj_w, proj_bn, out, CDIM, CCAT * NSP, CDIM * NSP);
}

// Round 2
// 738.653 us; speedup vs baseline: 2.3821x; 2.3821x over previous
//
#include <hip/hip_runtime.h>
#include <hip/hip_fp16.h>

#define NB 64
#define NSP 784
#define CDIM 512
#define CQK 256
#define C4 128
#define NHEADS 8
#define CCAT 1024
#define BN_EPS 1e-5f
#define ATT_SCALE 0.17677669529663687f  // 32^-0.5

using half8_t = __attribute__((ext_vector_type(8))) _Float16;
using half4_t = __attribute__((ext_vector_type(4))) _Float16;
using f32x4_t = __attribute__((ext_vector_type(4))) float;

__device__ __forceinline__ void bn_coef(const float* bn, int cout, int o, float& inv, float& add) {
    float g = bn[o], be = bn[cout + o], m = bn[2 * cout + o], v = bn[3 * cout + o];
    inv = g * rsqrtf(v + BN_EPS);
    add = be - m * inv;
}

// ---- x [64][512][784] f32 -> x_t [64*784][512] f16 ----
__global__ __launch_bounds__(256)
void transpose_x_kernel(const float* __restrict__ x, _Float16* __restrict__ xt)
{
    __shared__ _Float16 t[32 * 786];
    const int b = blockIdx.y, c0 = blockIdx.x * 32;
    const float* src = x + ((long)b * CDIM + c0) * NSP;
    for (int i = threadIdx.x; i < 32 * NSP; i += 256) {
        const int c = i / NSP, sp = i - c * NSP;
        t[c * 786 + sp] = (_Float16)src[i];
    }
    __syncthreads();
    _Float16* dst = xt + (long)b * NSP * CDIM + c0;
    for (int sp = threadIdx.x; sp < NSP; sp += 256) {
        half8_t* d8 = (half8_t*)(dst + (long)sp * CDIM);
#pragma unroll
        for (int q = 0; q < 4; ++q) {
            half8_t v;
#pragma unroll
            for (int j = 0; j < 8; ++j) v[j] = t[(q * 8 + j) * 786 + sp];
            d8[q] = v;
        }
    }
}

// ---- convert qk_w (131072) + vs_w (65536) + proj_w (524288) f32 -> f16 ----
__global__ __launch_bounds__(256)
void convert_w_kernel(const float* __restrict__ qk, const float* __restrict__ vs,
                      const float* __restrict__ pj, _Float16* __restrict__ dst)
{
    const int e = (blockIdx.x * 256 + threadIdx.x) * 4;
    const float* src; int off; _Float16* d;
    if (e < 131072)      { src = qk; off = e;          d = dst; }
    else if (e < 196608) { src = vs; off = e - 131072; d = dst + 131072; }
    else                 { src = pj; off = e - 196608; d = dst + 196608; }
    const float4 v = *(const float4*)(src + off);
    half4_t h; h[0] = (_Float16)v.x; h[1] = (_Float16)v.y; h[2] = (_Float16)v.z; h[3] = (_Float16)v.w;
    *(half4_t*)(d + off) = h;
}

// ---- MFMA GEMM: Out[o][col] = BN(sum_k W[o][k] * InT[col][k]) ----
// 128x128 tile, BK=64, 4 waves (2x2), 16x16x32 f16 MFMA, XOR-swizzled LDS.
// OUT_T=1: f16 out at out[col*cout + o] ; OUT_T=0: f32 out at [b][o][sp].
template<int CIN, bool BF32, bool OUT_T>
__global__ __launch_bounds__(256)
void mfma_gemm_kernel(const void* __restrict__ inB, const _Float16* __restrict__ wA,
                      const float* __restrict__ bnp, void* __restrict__ outp, int cout)
{
    __shared__ _Float16 As[8192];
    __shared__ _Float16 Bs[8192];
    const int tid = threadIdx.x;
    const int lane = tid & 63;
    const int wv = tid >> 6;
    const int wm = wv >> 1, wn = wv & 1;
    const int colBase = blockIdx.x * 128;
    const int oBase = blockIdx.y * 128;

    const _Float16* inH = (const _Float16*)inB;
    const float*    inF = (const float*)inB;

    f32x4_t acc[4][4];
#pragma unroll
    for (int i = 0; i < 4; ++i)
#pragma unroll
        for (int j = 0; j < 4; ++j) acc[i][j] = (f32x4_t){0.f, 0.f, 0.f, 0.f};

    for (int k0 = 0; k0 < CIN; k0 += 64) {
        if (k0) __syncthreads();
#pragma unroll
        for (int it = 0; it < 4; ++it) {
            const int c = it * 256 + tid;
            const int kg = c & 7, idx = c >> 3;
            const int slot = kg * 128 + (idx ^ kg);
            const half8_t av = *(const half8_t*)(wA + (long)(oBase + idx) * CIN + k0 + kg * 8);
            *(half8_t*)(As + slot * 8) = av;
            if constexpr (BF32) {
                const float* bp = inF + (long)(colBase + idx) * CIN + k0 + kg * 8;
                const float4 b0 = *(const float4*)bp;
                const float4 b1 = *(const float4*)(bp + 4);
                half8_t bv;
                bv[0] = (_Float16)b0.x; bv[1] = (_Float16)b0.y; bv[2] = (_Float16)b0.z; bv[3] = (_Float16)b0.w;
                bv[4] = (_Float16)b1.x; bv[5] = (_Float16)b1.y; bv[6] = (_Float16)b1.z; bv[7] = (_Float16)b1.w;
                *(half8_t*)(Bs + slot * 8) = bv;
            } else {
                const half8_t bv = *(const half8_t*)(inH + (long)(colBase + idx) * CIN + k0 + kg * 8);
                *(half8_t*)(Bs + slot * 8) = bv;
            }
        }
        __syncthreads();
#pragma unroll
        for (int ks = 0; ks < 2; ++ks) {
            const int kg = ks * 4 + (lane >> 4);
            half8_t a[4], b[4];
#pragma unroll
            for (int mf = 0; mf < 4; ++mf) {
                const int idx = wm * 64 + mf * 16 + (lane & 15);
                a[mf] = *(const half8_t*)(As + (kg * 128 + (idx ^ kg)) * 8);
            }
#pragma unroll
            for (int nf = 0; nf < 4; ++nf) {
                const int idx = wn * 64 + nf * 16 + (lane & 15);
                b[nf] = *(const half8_t*)(Bs + (kg * 128 + (idx ^ kg)) * 8);
            }
#pragma unroll
            for (int mf = 0; mf < 4; ++mf)
#pragma unroll
                for (int nf = 0; nf < 4; ++nf)
                    acc[mf][nf] = __builtin_amdgcn_mfma_f32_16x16x32_f16(a[mf], b[nf], acc[mf][nf], 0, 0, 0);
        }
    }

    const int rbase = wm * 64 + (lane >> 4) * 4;
    const int cbase = colBase + wn * 64 + (lane & 15);
#pragma unroll
    for (int mf = 0; mf < 4; ++mf) {
        const int o0 = oBase + rbase + mf * 16;
        float inv[4], add[4];
#pragma unroll
        for (int j = 0; j < 4; ++j) bn_coef(bnp, cout, o0 + j, inv[j], add[j]);
#pragma unroll
        for (int nf = 0; nf < 4; ++nf) {
            const int col = cbase + nf * 16;
            if constexpr (OUT_T) {
                _Float16* dst = (_Float16*)outp + (long)col * cout + o0;
                half4_t v;
#pragma unroll
                for (int j = 0; j < 4; ++j) v[j] = (_Float16)(acc[mf][nf][j] * inv[j] + add[j]);
                *(half4_t*)dst = v;
            } else {
                const int bb = col / NSP, sp = col - bb * NSP;
                float* dst = (float*)outp + ((long)bb * cout + o0) * NSP + sp;
#pragma unroll
                for (int j = 0; j < 4; ++j) dst[(long)j * NSP] = acc[mf][nf][j] * inv[j] + add[j];
            }
        }
    }
}

// ---- depthwise 5x5 SAME + BN; feat_t [sp][256] (q = c<128) -> qdw_t [sp][128] ----
__global__ __launch_bounds__(256)
void dwconv_t_kernel(const _Float16* __restrict__ feat_t, const float* __restrict__ dww,
                     const float* __restrict__ dwbn, _Float16* __restrict__ qdw_t)
{
    const int h = blockIdx.x, b = blockIdx.y;
    __shared__ _Float16 rows[5][28][128];
    __shared__ float wsh[128][25];
    for (int i = threadIdx.x; i < 5 * 28 * 128; i += 256) {
        const int dy = i / (28 * 128);
        const int rem = i - dy * (28 * 128);
        const int iw = rem >> 7, c = rem & 127;
        const int ih = h + dy - 2;
        _Float16 v = (_Float16)0.f;
        if (ih >= 0 && ih < 28) v = feat_t[((long)b * NSP + ih * 28 + iw) * CQK + c];
        rows[dy][iw][c] = v;
    }
    for (int i = threadIdx.x; i < 128 * 25; i += 256) wsh[i / 25][i % 25] = dww[i];
    __syncthreads();
    const int c = threadIdx.x & 127;
    float inv, add;
    bn_coef(dwbn, C4, c, inv, add);
    for (int l = threadIdx.x; l < 28 * 128; l += 256) {
        const int w = l >> 7;
        float acc = 0.f;
#pragma unroll
        for (int dy = 0; dy < 5; ++dy) {
#pragma unroll
            for (int dx = 0; dx < 5; ++dx) {
                const int iw = w + dx - 2;
                if (iw < 0 || iw >= 28) continue;
                acc += wsh[c][dy * 5 + dx] * (float)rows[dy][iw][c];
            }
        }
        qdw_t[((long)b * NSP + h * 28 + w) * C4 + c] = (_Float16)(acc * inv + add);
    }
}

// ---- attention maps. ROWMODE: fix=h, positions w (bias_w). else fix=w, positions h (bias_h). ----
template<bool ROWMODE>
__global__ __launch_bounds__(256)
void attn_map_kernel(const _Float16* __restrict__ qdw_t, const _Float16* __restrict__ feat_t,
                     const float* __restrict__ biasv, const int* __restrict__ bidx,
                     float* __restrict__ attn_out)
{
    const int fix = blockIdx.x, b = blockIdx.y;
    __shared__ float Qs[28][132];
    __shared__ float Ks[28][132];
    __shared__ float S[28][28];
    for (int l = threadIdx.x; l < 28 * 128; l += 256) {
        const int p = l >> 7, c = l & 127;
        const int sp = ROWMODE ? (fix * 28 + p) : (p * 28 + fix);
        Qs[p][c] = (float)qdw_t[((long)b * NSP + sp) * C4 + c];
        Ks[p][c] = (float)feat_t[((long)b * NSP + sp) * CQK + 128 + c];
    }
    __syncthreads();
    for (int e = threadIdx.x; e < 784; e += 256) {
        const int qp = e / 28, kp = e - (e / 28) * 28;
        float acc = 0.f;
#pragma unroll 8
        for (int c = 0; c < C4; ++c) acc += Qs[qp][c] * Ks[kp][c];
        S[qp][kp] = acc * ATT_SCALE + biasv[bidx[e]];
    }
    __syncthreads();
    if (threadIdx.x < 28) {
        const int r = threadIdx.x;
        float mx = -1e30f;
        for (int k = 0; k < 28; ++k) mx = fmaxf(mx, S[r][k]);
        float sum = 0.f;
        for (int k = 0; k < 28; ++k) { const float e2 = __expf(S[r][k] - mx); S[r][k] = e2; sum += e2; }
        const float rinv = 1.f / sum;
        float* dst = attn_out + (((long)b * 28 + fix) * 28 + r) * 28;
        for (int k = 0; k < 28; ++k) dst[k] = S[r][k] * rinv;
    }
}

// ---- casc[col][0:64) (f32) = (head==0 ? 0 : casc) + x_t[col][head*64 + 0:64) ----
__global__ __launch_bounds__(256)
void casc_kernel(const _Float16* __restrict__ xt, float* __restrict__ casc, int head)
{
    const long i8 = ((long)blockIdx.x * 256 + threadIdx.x) * 8;
    const long col = i8 >> 6;
    const int c = (int)(i8 & 63);
    const half8_t xv = *(const half8_t*)(xt + col * CDIM + head * 64 + c);
    float* cp = casc + i8;
    if (head == 0) {
#pragma unroll
        for (int j = 0; j < 8; ++j) cp[j] = (float)xv[j];
    } else {
#pragma unroll
        for (int j = 0; j < 8; ++j) cp[j] += (float)xv[j];
    }
}

// ---- row attention, in place on vout [sp][128]. Block = (h-row, b). ----
__global__ __launch_bounds__(256)
void stage1_kernel(_Float16* __restrict__ vout, const float* __restrict__ attnw)
{
    const int hrow = blockIdx.x, b = blockIdx.y;
    __shared__ float Vs[28][128];
    __shared__ float A[784];
    _Float16* base = vout + ((long)b * NSP + hrow * 28) * C4;
    for (int l = threadIdx.x; l < 28 * 128; l += 256) Vs[l >> 7][l & 127] = (float)base[l];
    for (int l = threadIdx.x; l < 784; l += 256) A[l] = attnw[((long)b * 28 + hrow) * 784 + l];
    __syncthreads();
    for (int l = threadIdx.x; l < 28 * 128; l += 256) {
        const int w = l >> 7, d = l & 127;
        float acc = 0.f;
#pragma unroll
        for (int j = 0; j < 28; ++j) acc += A[w * 28 + j] * Vs[j][d];
        base[l] = (_Float16)acc;
    }
}

// ---- column attention + ReLU -> concat_t [sp][1024]. Block = (w-col, b). ----
__global__ __launch_bounds__(256)
void stage2_kernel(const _Float16* __restrict__ vout, const float* __restrict__ attnh,
                   _Float16* __restrict__ concat_t, int head)
{
    const int w = blockIdx.x, b = blockIdx.y;
    __shared__ float Ms[28][128];
    __shared__ float A[784];
    for (int l = threadIdx.x; l < 28 * 128; l += 256) {
        const int kk = l >> 7, d = l & 127;
        Ms[kk][d] = (float)vout[((long)b * NSP + kk * 28 + w) * C4 + d];
    }
    for (int l = threadIdx.x; l < 784; l += 256) A[l] = attnh[((long)b * 28 + w) * 784 + l];
    __syncthreads();
    for (int l = threadIdx.x; l < 28 * 128; l += 256) {
        const int h = l >> 7, d = l & 127;
        float acc = 0.f;
#pragma unroll
        for (int kk = 0; kk < 28; ++kk) acc += A[h * 28 + kk] * Ms[kk][d];
        concat_t[((long)b * NSP + h * 28 + w) * CCAT + head * C4 + d] = (_Float16)fmaxf(acc, 0.f);
    }
}

extern "C" void kernel_launch(void* const* d_in, const int* in_sizes, int n_in,
                              void* d_out, int out_size, void* d_ws, size_t ws_size,
                              hipStream_t stream)
{
    const float* x        = (const float*)d_in[0];
    const float* qk_w     = (const float*)d_in[1];
    const float* qk_bn    = (const float*)d_in[2];
    const float* dws_w    = (const float*)d_in[3];
    const float* dws_bn   = (const float*)d_in[4];
    const float* vs_w     = (const float*)d_in[5];
    const float* vs_bn    = (const float*)d_in[6];
    const float* proj_w   = (const float*)d_in[7];
    const float* proj_bn  = (const float*)d_in[8];
    const float* bias_h   = (const float*)d_in[9];
    const float* bias_w   = (const float*)d_in[10];
    const int*   bias_idx = (const int*)d_in[11];

    // --- scratch inside d_out (fully overwritten by proj GEMM at the end) ---
    char* ob = (char*)d_out;
    _Float16* x_t    = (_Float16*)ob;                    // 51,380,224 B
    float*    attw   = (float*)(ob + 51380224);          //  5,619,712 B
    float*    atth   = (float*)(ob + 56999936);          //  5,619,712 B -> 62,619,648
    _Float16* feat_t = (_Float16*)(ob + 62619648);       // 25,690,112 B -> 88,309,760
    _Float16* qdw_t  = (_Float16*)(ob + 88309760);       // 12,845,056 B -> 101,154,816
    float*    casc   = (float*)(ob + 62619648);          // aliases feat_t (dead) 12,845,056 B
    _Float16* vout   = (_Float16*)(ob + 75464704);       // 12,845,056 B -> 88,309,760

    // --- ws: concat_t + f16 weights ---
    _Float16* concat_t = (_Float16*)d_ws;                           // 102,760,448 B
    _Float16* w_h      = (_Float16*)((char*)d_ws + 102760448);      // 1,441,792 B
    _Float16* qk_w_h   = w_h;
    _Float16* vs_w_h   = w_h + 131072;
    _Float16* proj_w_h = w_h + 196608;

    transpose_x_kernel<<<dim3(16, NB), 256, 0, stream>>>(x, x_t);
    convert_w_kernel<<<704, 256, 0, stream>>>(qk_w, vs_w, proj_w, w_h);

    // feat_t = BN(qk_w @ x)   [sp][256] f16
    mfma_gemm_kernel<CDIM, false, true><<<dim3(392, 2), 256, 0, stream>>>(
        x_t, qk_w_h, qk_bn, feat_t, CQK);
    dwconv_t_kernel<<<dim3(28, NB), 256, 0, stream>>>(feat_t, dws_w, dws_bn, qdw_t);
    attn_map_kernel<true><<<dim3(28, NB), 256, 0, stream>>>(qdw_t, feat_t, bias_w, bias_idx, attw);
    attn_map_kernel<false><<<dim3(28, NB), 256, 0, stream>>>(qdw_t, feat_t, bias_h, bias_idx, atth);

    for (int head = 0; head < NHEADS; ++head) {
        casc_kernel<<<1568, 256, 0, stream>>>(x_t, casc, head);
        mfma_gemm_kernel<64, true, true><<<dim3(392, 1), 256, 0, stream>>>(
            casc, vs_w_h + head * C4 * 64, vs_bn + head * 4 * C4, vout, C4);
        stage1_kernel<<<dim3(28, NB), 256, 0, stream>>>(vout, attw);
        stage2_kernel<<<dim3(28, NB), 256, 0, stream>>>(vout, atth, concat_t, head);
    }

    // out = BN(proj_w @ relu(concat))  (relu folded into stage2)
    mfma_gemm_kernel<CCAT, false, false><<<dim3(392, 4), 256, 0, stream>>>(
        concat_t, proj_w_h, proj_bn, (float*)d_out, CDIM);
}

// Round 3
// 474.437 us; speedup vs baseline: 3.7086x; 1.5569x over previous
//
#include <hip/hip_runtime.h>
#include <hip/hip_fp16.h>

#define NB 64
#define NSP 784
#define CDIM 512
#define CQK 256
#define C4 128
#define NHEADS 8
#define CCAT 1024
#define BN_EPS 1e-5f
#define ATT_SCALE 0.17677669529663687f  // 32^-0.5

using half8_t = __attribute__((ext_vector_type(8))) _Float16;
using half4_t = __attribute__((ext_vector_type(4))) _Float16;
using half2_t = __attribute__((ext_vector_type(2))) _Float16;
using f32x4_t = __attribute__((ext_vector_type(4))) float;

__device__ __forceinline__ void bn_coef(const float* bn, int cout, int o, float& inv, float& add) {
    float g = bn[o], be = bn[cout + o], m = bn[2 * cout + o], v = bn[3 * cout + o];
    inv = g * rsqrtf(v + BN_EPS);
    add = be - m * inv;
}

__device__ __forceinline__ float fdot2(half2_t a, half2_t b, float c) {
#if __has_builtin(__builtin_amdgcn_fdot2)
    return __builtin_amdgcn_fdot2(a, b, c, false);
#else
    return c + (float)a[0] * (float)b[0] + (float)a[1] * (float)b[1];
#endif
}

// ---- x [64][512][784] f32 -> x_t [64*784][512] f16 ----
__global__ __launch_bounds__(256)
void transpose_x_kernel(const float* __restrict__ x, _Float16* __restrict__ xt)
{
    __shared__ _Float16 t[32 * 786];
    const int b = blockIdx.y, c0 = blockIdx.x * 32;
    const float* src = x + ((long)b * CDIM + c0) * NSP;
    for (int i = threadIdx.x; i < 32 * NSP; i += 256) {
        const int c = i / NSP, sp = i - c * NSP;
        t[c * 786 + sp] = (_Float16)src[i];
    }
    __syncthreads();
    _Float16* dst = xt + (long)b * NSP * CDIM + c0;
    for (int sp = threadIdx.x; sp < NSP; sp += 256) {
        half8_t* d8 = (half8_t*)(dst + (long)sp * CDIM);
#pragma unroll
        for (int q = 0; q < 4; ++q) {
            half8_t v;
#pragma unroll
            for (int j = 0; j < 8; ++j) v[j] = t[(q * 8 + j) * 786 + sp];
            d8[q] = v;
        }
    }
}

// ---- convert qk_w (131072) + vs_w (65536) + proj_w (524288) f32 -> f16 ----
__global__ __launch_bounds__(256)
void convert_w_kernel(const float* __restrict__ qk, const float* __restrict__ vs,
                      const float* __restrict__ pj, _Float16* __restrict__ dst)
{
    const int e = (blockIdx.x * 256 + threadIdx.x) * 4;
    const float* src; int off; _Float16* d;
    if (e < 131072)      { src = qk; off = e;          d = dst; }
    else if (e < 196608) { src = vs; off = e - 131072; d = dst + 131072; }
    else                 { src = pj; off = e - 196608; d = dst + 196608; }
    const float4 v = *(const float4*)(src + off);
    half4_t h; h[0] = (_Float16)v.x; h[1] = (_Float16)v.y; h[2] = (_Float16)v.z; h[3] = (_Float16)v.w;
    *(half4_t*)(d + off) = h;
}

// ---- MFMA GEMM: Out[o][col] = BN(sum_k W[o][k] * InT[col][k]) ----
// 128x128 tile, BK=64, 4 waves (2x2), 16x16x32 f16 MFMA, XOR-swizzled LDS.
template<int CIN, bool OUT_T>
__global__ __launch_bounds__(256)
void mfma_gemm_kernel(const _Float16* __restrict__ inH, const _Float16* __restrict__ wA,
                      const float* __restrict__ bnp, void* __restrict__ outp, int cout)
{
    __shared__ _Float16 As[8192];
    __shared__ _Float16 Bs[8192];
    const int tid = threadIdx.x;
    const int lane = tid & 63;
    const int wv = tid >> 6;
    const int wm = wv >> 1, wn = wv & 1;
    const int colBase = blockIdx.x * 128;
    const int oBase = blockIdx.y * 128;

    f32x4_t acc[4][4];
#pragma unroll
    for (int i = 0; i < 4; ++i)
#pragma unroll
        for (int j = 0; j < 4; ++j) acc[i][j] = (f32x4_t){0.f, 0.f, 0.f, 0.f};

    for (int k0 = 0; k0 < CIN; k0 += 64) {
        if (k0) __syncthreads();
#pragma unroll
        for (int it = 0; it < 4; ++it) {
            const int c = it * 256 + tid;
            const int kg = c & 7, idx = c >> 3;
            const int slot = kg * 128 + (idx ^ kg);
            const half8_t av = *(const half8_t*)(wA + (long)(oBase + idx) * CIN + k0 + kg * 8);
            *(half8_t*)(As + slot * 8) = av;
            const half8_t bv = *(const half8_t*)(inH + (long)(colBase + idx) * CIN + k0 + kg * 8);
            *(half8_t*)(Bs + slot * 8) = bv;
        }
        __syncthreads();
#pragma unroll
        for (int ks = 0; ks < 2; ++ks) {
            const int kg = ks * 4 + (lane >> 4);
            half8_t a[4], b[4];
#pragma unroll
            for (int mf = 0; mf < 4; ++mf) {
                const int idx = wm * 64 + mf * 16 + (lane & 15);
                a[mf] = *(const half8_t*)(As + (kg * 128 + (idx ^ kg)) * 8);
            }
#pragma unroll
            for (int nf = 0; nf < 4; ++nf) {
                const int idx = wn * 64 + nf * 16 + (lane & 15);
                b[nf] = *(const half8_t*)(Bs + (kg * 128 + (idx ^ kg)) * 8);
            }
#pragma unroll
            for (int mf = 0; mf < 4; ++mf)
#pragma unroll
                for (int nf = 0; nf < 4; ++nf)
                    acc[mf][nf] = __builtin_amdgcn_mfma_f32_16x16x32_f16(a[mf], b[nf], acc[mf][nf], 0, 0, 0);
        }
    }

    const int rbase = wm * 64 + (lane >> 4) * 4;
    const int cbase = colBase + wn * 64 + (lane & 15);
#pragma unroll
    for (int mf = 0; mf < 4; ++mf) {
        const int o0 = oBase + rbase + mf * 16;
        float inv[4], add[4];
#pragma unroll
        for (int j = 0; j < 4; ++j) bn_coef(bnp, cout, o0 + j, inv[j], add[j]);
#pragma unroll
        for (int nf = 0; nf < 4; ++nf) {
            const int col = cbase + nf * 16;
            if constexpr (OUT_T) {
                _Float16* dst = (_Float16*)outp + (long)col * cout + o0;
                half4_t v;
#pragma unroll
                for (int j = 0; j < 4; ++j) v[j] = (_Float16)(acc[mf][nf][j] * inv[j] + add[j]);
                *(half4_t*)dst = v;
            } else {
                const int bb = col / NSP, sp = col - bb * NSP;
                float* dst = (float*)outp + ((long)bb * cout + o0) * NSP + sp;
#pragma unroll
                for (int j = 0; j < 4; ++j) dst[(long)j * NSP] = acc[mf][nf][j] * inv[j] + add[j];
            }
        }
    }
}

// ---- vall: per 128-col tile, prefix-sum x_t slices in f32 regs; per head MFMA with
//      W_h and write BN'd f16 into concat_t[col][head*128+o]. Replaces casc+vGEMM x8. ----
__global__ __launch_bounds__(256)
void vall_kernel(const _Float16* __restrict__ xt, const _Float16* __restrict__ vsw,
                 const float* __restrict__ vsbn, _Float16* __restrict__ concat_t)
{
    __shared__ _Float16 As[8192];
    __shared__ _Float16 Bs[8192];
    const int tid = threadIdx.x, lane = tid & 63;
    const int wv = tid >> 6, wm = wv >> 1, wn = wv & 1;
    const int colBase = blockIdx.x * 128;

    float bacc[4][8];
#pragma unroll
    for (int it = 0; it < 4; ++it)
#pragma unroll
        for (int j = 0; j < 8; ++j) bacc[it][j] = 0.f;

    for (int head = 0; head < NHEADS; ++head) {
        if (head) __syncthreads();
#pragma unroll
        for (int it = 0; it < 4; ++it) {
            const int c = it * 256 + tid;
            const int kg = c & 7, idx = c >> 3;
            const int slot = kg * 128 + (idx ^ kg);
            const half8_t xv = *(const half8_t*)(xt + (long)(colBase + idx) * CDIM + head * 64 + kg * 8);
            half8_t bv;
#pragma unroll
            for (int j = 0; j < 8; ++j) { bacc[it][j] += (float)xv[j]; bv[j] = (_Float16)bacc[it][j]; }
            *(half8_t*)(Bs + slot * 8) = bv;
            const half8_t av = *(const half8_t*)(vsw + (long)head * (C4 * 64) + idx * 64 + kg * 8);
            *(half8_t*)(As + slot * 8) = av;
        }
        __syncthreads();

        f32x4_t acc[4][4];
#pragma unroll
        for (int i = 0; i < 4; ++i)
#pragma unroll
            for (int j = 0; j < 4; ++j) acc[i][j] = (f32x4_t){0.f, 0.f, 0.f, 0.f};
#pragma unroll
        for (int ks = 0; ks < 2; ++ks) {
            const int kg = ks * 4 + (lane >> 4);
            half8_t a[4], b[4];
#pragma unroll
            for (int mf = 0; mf < 4; ++mf) {
                const int idx = wm * 64 + mf * 16 + (lane & 15);
                a[mf] = *(const half8_t*)(As + (kg * 128 + (idx ^ kg)) * 8);
            }
#pragma unroll
            for (int nf = 0; nf < 4; ++nf) {
                const int idx = wn * 64 + nf * 16 + (lane & 15);
                b[nf] = *(const half8_t*)(Bs + (kg * 128 + (idx ^ kg)) * 8);
            }
#pragma unroll
            for (int mf = 0; mf < 4; ++mf)
#pragma unroll
                for (int nf = 0; nf < 4; ++nf)
                    acc[mf][nf] = __builtin_amdgcn_mfma_f32_16x16x32_f16(a[mf], b[nf], acc[mf][nf], 0, 0, 0);
        }

        const int rbase = wm * 64 + (lane >> 4) * 4;
        const int cbase = colBase + wn * 64 + (lane & 15);
        const float* bnh = vsbn + head * 4 * C4;
#pragma unroll
        for (int mf = 0; mf < 4; ++mf) {
            const int o0 = rbase + mf * 16;
            float inv[4], add[4];
#pragma unroll
            for (int j = 0; j < 4; ++j) bn_coef(bnh, C4, o0 + j, inv[j], add[j]);
#pragma unroll
            for (int nf = 0; nf < 4; ++nf) {
                const int col = cbase + nf * 16;
                _Float16* dst = concat_t + (long)col * CCAT + head * C4 + o0;
                half4_t v;
#pragma unroll
                for (int j = 0; j < 4; ++j) v[j] = (_Float16)(acc[mf][nf][j] * inv[j] + add[j]);
                *(half4_t*)dst = v;
            }
        }
    }
}

// ---- depthwise 5x5 SAME + BN; feat_t [sp][256] (q = c<128) -> qdw_t [sp][128] ----
// block = (h, b, chalf). Zero-padded halo in LDS, per-thread fixed channel pair, f32 weights in regs.
__global__ __launch_bounds__(256)
void dwconv_t_kernel(const _Float16* __restrict__ feat_t, const float* __restrict__ dww,
                     const float* __restrict__ dwbn, _Float16* __restrict__ qdw_t)
{
    const int h = blockIdx.x, b = blockIdx.y, ch0 = blockIdx.z * 64;
    __shared__ _Float16 rows[5][32][64];  // [dy][iw+2][c], borders zero
    for (int i = threadIdx.x; i < 5 * 32 * 64; i += 256) {
        const int dy = i / (32 * 64);
        const int rem = i - dy * (32 * 64);
        const int iw = rem >> 6, c = rem & 63;
        const int ih = h + dy - 2, w = iw - 2;
        _Float16 v = (_Float16)0.f;
        if (ih >= 0 && ih < 28 && w >= 0 && w < 28)
            v = feat_t[((long)b * NSP + ih * 28 + w) * CQK + ch0 + c];
        rows[dy][iw][c] = v;
    }
    const int pr = threadIdx.x & 31;          // channel pair, fixed per thread
    const int c2 = pr * 2;
    float wr0[25], wr1[25];
#pragma unroll
    for (int q = 0; q < 25; ++q) {
        wr0[q] = dww[(ch0 + c2) * 25 + q];
        wr1[q] = dww[(ch0 + c2 + 1) * 25 + q];
    }
    float inv0, add0, inv1, add1;
    bn_coef(dwbn, C4, ch0 + c2, inv0, add0);
    bn_coef(dwbn, C4, ch0 + c2 + 1, inv1, add1);
    __syncthreads();
    for (int l = threadIdx.x; l < 28 * 32; l += 256) {
        const int w = l >> 5;
        float a0 = 0.f, a1 = 0.f;
#pragma unroll
        for (int dy = 0; dy < 5; ++dy)
#pragma unroll
            for (int dx = 0; dx < 5; ++dx) {
                const half2_t v2 = *(const half2_t*)(&rows[dy][w + dx][c2]);
                a0 += wr0[dy * 5 + dx] * (float)v2[0];
                a1 += wr1[dy * 5 + dx] * (float)v2[1];
            }
        half2_t o2; o2[0] = (_Float16)(a0 * inv0 + add0); o2[1] = (_Float16)(a1 * inv1 + add1);
        *(half2_t*)(qdw_t + ((long)b * NSP + h * 28 + w) * C4 + ch0 + c2) = o2;
    }
}

// ---- attention maps. ROWMODE: fix=h, positions w (bias_w). else fix=w, positions h (bias_h). ----
template<bool ROWMODE>
__global__ __launch_bounds__(256)
void attn_map_kernel(const _Float16* __restrict__ qdw_t, const _Float16* __restrict__ feat_t,
                     const float* __restrict__ biasv, float* __restrict__ attn_out)
{
    const int fix = blockIdx.x, b = blockIdx.y;
    __shared__ _Float16 Qs[28][136];
    __shared__ _Float16 Ks[28][136];
    __shared__ float S[28][28];
    __shared__ float bsh[28];
    if (threadIdx.x < 28) bsh[threadIdx.x] = biasv[threadIdx.x];
    for (int l = threadIdx.x; l < 28 * 16; l += 256) {
        const int p = l >> 4, c8 = (l & 15) * 8;
        const int sp = ROWMODE ? (fix * 28 + p) : (p * 28 + fix);
        *(half8_t*)(&Qs[p][c8]) = *(const half8_t*)(qdw_t + ((long)b * NSP + sp) * C4 + c8);
        *(half8_t*)(&Ks[p][c8]) = *(const half8_t*)(feat_t + ((long)b * NSP + sp) * CQK + 128 + c8);
    }
    __syncthreads();
    for (int e = threadIdx.x; e < 784; e += 256) {
        const int qp = e / 28, kp = e - (e / 28) * 28;
        float acc = 0.f;
        const half2_t* qv = (const half2_t*)&Qs[qp][0];
        const half2_t* kv = (const half2_t*)&Ks[kp][0];
#pragma unroll
        for (int c = 0; c < 64; ++c) acc = fdot2(qv[c], kv[c], acc);
        const int dd = qp - kp;
        S[qp][kp] = acc * ATT_SCALE + bsh[dd < 0 ? -dd : dd];
    }
    __syncthreads();
    const int r = threadIdx.x >> 3, g = threadIdx.x & 7;
    if (r < 28) {
        float mx = -1e30f;
#pragma unroll
        for (int j = 0; j < 4; ++j) { const int k = g + j * 8; if (k < 28) mx = fmaxf(mx, S[r][k]); }
        mx = fmaxf(mx, __shfl_xor(mx, 1));
        mx = fmaxf(mx, __shfl_xor(mx, 2));
        mx = fmaxf(mx, __shfl_xor(mx, 4));
        float e4[4], sum = 0.f;
#pragma unroll
        for (int j = 0; j < 4; ++j) {
            const int k = g + j * 8;
            e4[j] = (k < 28) ? __expf(S[r][k] - mx) : 0.f;
            sum += e4[j];
        }
        sum += __shfl_xor(sum, 1);
        sum += __shfl_xor(sum, 2);
        sum += __shfl_xor(sum, 4);
        const float rinv = 1.f / sum;
        float* dst = attn_out + (((long)b * 28 + fix) * 28 + r) * 28;
#pragma unroll
        for (int j = 0; j < 4; ++j) { const int k = g + j * 8; if (k < 28) dst[k] = e4[j] * rinv; }
    }
}

// ---- row attention, in place on concat_t slice. Block = (h-row, b, head). ----
__global__ __launch_bounds__(256)
void stage1_kernel(_Float16* __restrict__ concat_t, const float* __restrict__ attnw)
{
    const int hrow = blockIdx.x, b = blockIdx.y, head = blockIdx.z;
    __shared__ float Vs[28][128];
    __shared__ float A[784];
    _Float16* base = concat_t + ((long)b * NSP + hrow * 28) * CCAT + head * C4;
    for (int l = threadIdx.x; l < 28 * 128; l += 256) {
        const int j = l >> 7, d = l & 127;
        Vs[j][d] = (float)base[(long)j * CCAT + d];
    }
    for (int l = threadIdx.x; l < 784; l += 256) A[l] = attnw[((long)b * 28 + hrow) * 784 + l];
    __syncthreads();
    for (int l = threadIdx.x; l < 28 * 128; l += 256) {
        const int w = l >> 7, d = l & 127;
        float acc = 0.f;
#pragma unroll
        for (int j = 0; j < 28; ++j) acc += A[w * 28 + j] * Vs[j][d];
        base[(long)w * CCAT + d] = (_Float16)acc;
    }
}

// ---- column attention + ReLU, in place. Block = (w-col, b, head). ----
__global__ __launch_bounds__(256)
void stage2_kernel(_Float16* __restrict__ concat_t, const float* __restrict__ attnh)
{
    const int w = blockIdx.x, b = blockIdx.y, head = blockIdx.z;
    __shared__ float Ms[28][128];
    __shared__ float A[784];
    _Float16* base = concat_t + ((long)b * NSP + w) * CCAT + head * C4;
    for (int l = threadIdx.x; l < 28 * 128; l += 256) {
        const int kk = l >> 7, d = l & 127;
        Ms[kk][d] = (float)base[(long)kk * 28 * CCAT + d];
    }
    for (int l = threadIdx.x; l < 784; l += 256) A[l] = attnh[((long)b * 28 + w) * 784 + l];
    __syncthreads();
    for (int l = threadIdx.x; l < 28 * 128; l += 256) {
        const int h = l >> 7, d = l & 127;
        float acc = 0.f;
#pragma unroll
        for (int kk = 0; kk < 28; ++kk) acc += A[h * 28 + kk] * Ms[kk][d];
        base[(long)h * 28 * CCAT + d] = (_Float16)fmaxf(acc, 0.f);
    }
}

extern "C" void kernel_launch(void* const* d_in, const int* in_sizes, int n_in,
                              void* d_out, int out_size, void* d_ws, size_t ws_size,
                              hipStream_t stream)
{
    const float* x        = (const float*)d_in[0];
    const float* qk_w     = (const float*)d_in[1];
    const float* qk_bn    = (const float*)d_in[2];
    const float* dws_w    = (const float*)d_in[3];
    const float* dws_bn   = (const float*)d_in[4];
    const float* vs_w     = (const float*)d_in[5];
    const float* vs_bn    = (const float*)d_in[6];
    const float* proj_w   = (const float*)d_in[7];
    const float* proj_bn  = (const float*)d_in[8];
    const float* bias_h   = (const float*)d_in[9];
    const float* bias_w   = (const float*)d_in[10];

    // --- scratch inside d_out (fully overwritten by proj GEMM at the end) ---
    char* ob = (char*)d_out;
    _Float16* x_t    = (_Float16*)ob;                    // 51,380,224 B
    float*    attw   = (float*)(ob + 51380224);          //  5,619,712 B
    float*    atth   = (float*)(ob + 56999936);          //  5,619,712 B -> 62,619,648
    _Float16* feat_t = (_Float16*)(ob + 62619648);       // 25,690,112 B -> 88,309,760
    _Float16* qdw_t  = (_Float16*)(ob + 88309760);       // 12,845,056 B -> 101,154,816

    // --- ws: concat_t + f16 weights ---
    _Float16* concat_t = (_Float16*)d_ws;                           // 102,760,448 B
    _Float16* w_h      = (_Float16*)((char*)d_ws + 102760448);      // 1,441,792 B
    _Float16* qk_w_h   = w_h;
    _Float16* vs_w_h   = w_h + 131072;
    _Float16* proj_w_h = w_h + 196608;

    transpose_x_kernel<<<dim3(16, NB), 256, 0, stream>>>(x, x_t);
    convert_w_kernel<<<704, 256, 0, stream>>>(qk_w, vs_w, proj_w, w_h);

    // feat_t = BN(qk_w @ x)   [sp][256] f16
    mfma_gemm_kernel<CDIM, true><<<dim3(392, 2), 256, 0, stream>>>(
        x_t, qk_w_h, qk_bn, feat_t, CQK);
    dwconv_t_kernel<<<dim3(28, NB, 2), 256, 0, stream>>>(feat_t, dws_w, dws_bn, qdw_t);
    attn_map_kernel<true><<<dim3(28, NB), 256, 0, stream>>>(qdw_t, feat_t, bias_w, attw);
    attn_map_kernel<false><<<dim3(28, NB), 256, 0, stream>>>(qdw_t, feat_t, bias_h, atth);

    // all-heads V GEMM with on-the-fly prefix-summed cascade input
    vall_kernel<<<392, 256, 0, stream>>>(x_t, vs_w_h, vs_bn, concat_t);

    // attention applies, batched over heads, in place on concat_t
    stage1_kernel<<<dim3(28, NB, NHEADS), 256, 0, stream>>>(concat_t, attw);
    stage2_kernel<<<dim3(28, NB, NHEADS), 256, 0, stream>>>(concat_t, atth);

    // out = BN(proj_w @ relu(concat))  (relu folded into stage2)
    mfma_gemm_kernel<CCAT, false><<<dim3(392, 4), 256, 0, stream>>>(
        concat_t, proj_w_h, proj_bn, (float*)d_out, CDIM);
}

// Round 4
// 437.567 us; speedup vs baseline: 4.0211x; 1.0843x over previous
//
#include <hip/hip_runtime.h>
#include <hip/hip_fp16.h>

#define NB 64
#define NSP 784
#define CDIM 512
#define CQK 256
#define C4 128
#define NHEADS 8
#define CCAT 1024
#define BN_EPS 1e-5f
#define ATT_SCALE 0.17677669529663687f  // 32^-0.5

using half8_t = __attribute__((ext_vector_type(8))) _Float16;
using half4_t = __attribute__((ext_vector_type(4))) _Float16;
using half2_t = __attribute__((ext_vector_type(2))) _Float16;
using f32x4_t = __attribute__((ext_vector_type(4))) float;

__device__ __forceinline__ void bn_coef(const float* bn, int cout, int o, float& inv, float& add) {
    float g = bn[o], be = bn[cout + o], m = bn[2 * cout + o], v = bn[3 * cout + o];
    inv = g * rsqrtf(v + BN_EPS);
    add = be - m * inv;
}

__device__ __forceinline__ float fdot2(half2_t a, half2_t b, float c) {
#if __has_builtin(__builtin_amdgcn_fdot2)
    return __builtin_amdgcn_fdot2(a, b, c, false);
#else
    return c + (float)a[0] * (float)b[0] + (float)a[1] * (float)b[1];
#endif
}

// ---- x [64][512][784] f32 -> x_t [64*784][512] f16 ----
__global__ __launch_bounds__(256)
void transpose_x_kernel(const float* __restrict__ x, _Float16* __restrict__ xt)
{
    __shared__ _Float16 t[32 * 786];
    const int b = blockIdx.y, c0 = blockIdx.x * 32;
    const float* src = x + ((long)b * CDIM + c0) * NSP;
    for (int i = threadIdx.x; i < 32 * NSP; i += 256) {
        const int c = i / NSP, sp = i - c * NSP;
        t[c * 786 + sp] = (_Float16)src[i];
    }
    __syncthreads();
    _Float16* dst = xt + (long)b * NSP * CDIM + c0;
    for (int sp = threadIdx.x; sp < NSP; sp += 256) {
        half8_t* d8 = (half8_t*)(dst + (long)sp * CDIM);
#pragma unroll
        for (int q = 0; q < 4; ++q) {
            half8_t v;
#pragma unroll
            for (int j = 0; j < 8; ++j) v[j] = t[(q * 8 + j) * 786 + sp];
            d8[q] = v;
        }
    }
}

// ---- convert qk_w (131072) + vs_w (65536) + proj_w (524288) f32 -> f16 ----
__global__ __launch_bounds__(256)
void convert_w_kernel(const float* __restrict__ qk, const float* __restrict__ vs,
                      const float* __restrict__ pj, _Float16* __restrict__ dst)
{
    const int e = (blockIdx.x * 256 + threadIdx.x) * 4;
    const float* src; int off; _Float16* d;
    if (e < 131072)      { src = qk; off = e;          d = dst; }
    else if (e < 196608) { src = vs; off = e - 131072; d = dst + 131072; }
    else                 { src = pj; off = e - 196608; d = dst + 196608; }
    const float4 v = *(const float4*)(src + off);
    half4_t h; h[0] = (_Float16)v.x; h[1] = (_Float16)v.y; h[2] = (_Float16)v.z; h[3] = (_Float16)v.w;
    *(half4_t*)(d + off) = h;
}

// ---- MFMA GEMM: Out[o][col] = BN(sum_k W[o][k] * InT[col][k]) ----
// 128x128 tile, BK=64, 4 waves (2x2), 16x16x32 f16 MFMA, XOR-swizzled LDS.
template<int CIN, bool OUT_T>
__global__ __launch_bounds__(256)
void mfma_gemm_kernel(const _Float16* __restrict__ inH, const _Float16* __restrict__ wA,
                      const float* __restrict__ bnp, void* __restrict__ outp, int cout)
{
    __shared__ _Float16 As[8192];
    __shared__ _Float16 Bs[8192];
    const int tid = threadIdx.x;
    const int lane = tid & 63;
    const int wv = tid >> 6;
    const int wm = wv >> 1, wn = wv & 1;
    const int colBase = blockIdx.x * 128;
    const int oBase = blockIdx.y * 128;

    f32x4_t acc[4][4];
#pragma unroll
    for (int i = 0; i < 4; ++i)
#pragma unroll
        for (int j = 0; j < 4; ++j) acc[i][j] = (f32x4_t){0.f, 0.f, 0.f, 0.f};

    for (int k0 = 0; k0 < CIN; k0 += 64) {
        if (k0) __syncthreads();
#pragma unroll
        for (int it = 0; it < 4; ++it) {
            const int c = it * 256 + tid;
            const int kg = c & 7, idx = c >> 3;
            const int slot = kg * 128 + (idx ^ kg);
            const half8_t av = *(const half8_t*)(wA + (long)(oBase + idx) * CIN + k0 + kg * 8);
            *(half8_t*)(As + slot * 8) = av;
            const half8_t bv = *(const half8_t*)(inH + (long)(colBase + idx) * CIN + k0 + kg * 8);
            *(half8_t*)(Bs + slot * 8) = bv;
        }
        __syncthreads();
#pragma unroll
        for (int ks = 0; ks < 2; ++ks) {
            const int kg = ks * 4 + (lane >> 4);
            half8_t a[4], b[4];
#pragma unroll
            for (int mf = 0; mf < 4; ++mf) {
                const int idx = wm * 64 + mf * 16 + (lane & 15);
                a[mf] = *(const half8_t*)(As + (kg * 128 + (idx ^ kg)) * 8);
            }
#pragma unroll
            for (int nf = 0; nf < 4; ++nf) {
                const int idx = wn * 64 + nf * 16 + (lane & 15);
                b[nf] = *(const half8_t*)(Bs + (kg * 128 + (idx ^ kg)) * 8);
            }
#pragma unroll
            for (int mf = 0; mf < 4; ++mf)
#pragma unroll
                for (int nf = 0; nf < 4; ++nf)
                    acc[mf][nf] = __builtin_amdgcn_mfma_f32_16x16x32_f16(a[mf], b[nf], acc[mf][nf], 0, 0, 0);
        }
    }

    const int rbase = wm * 64 + (lane >> 4) * 4;
    const int cbase = colBase + wn * 64 + (lane & 15);
#pragma unroll
    for (int mf = 0; mf < 4; ++mf) {
        const int o0 = oBase + rbase + mf * 16;
        float inv[4], add[4];
#pragma unroll
        for (int j = 0; j < 4; ++j) bn_coef(bnp, cout, o0 + j, inv[j], add[j]);
#pragma unroll
        for (int nf = 0; nf < 4; ++nf) {
            const int col = cbase + nf * 16;
            if constexpr (OUT_T) {
                _Float16* dst = (_Float16*)outp + (long)col * cout + o0;
                half4_t v;
#pragma unroll
                for (int j = 0; j < 4; ++j) v[j] = (_Float16)(acc[mf][nf][j] * inv[j] + add[j]);
                *(half4_t*)dst = v;
            } else {
                const int bb = col / NSP, sp = col - bb * NSP;
                float* dst = (float*)outp + ((long)bb * cout + o0) * NSP + sp;
#pragma unroll
                for (int j = 0; j < 4; ++j) dst[(long)j * NSP] = acc[mf][nf][j] * inv[j] + add[j];
            }
        }
    }
}

// ---- vall: per 128-col tile, prefix-sum x_t slices in f32 regs; per head MFMA with
//      W_h and write BN'd f16 into concat_t[col][head*128+o]. Replaces casc+vGEMM x8. ----
__global__ __launch_bounds__(256)
void vall_kernel(const _Float16* __restrict__ xt, const _Float16* __restrict__ vsw,
                 const float* __restrict__ vsbn, _Float16* __restrict__ concat_t)
{
    __shared__ _Float16 As[8192];
    __shared__ _Float16 Bs[8192];
    const int tid = threadIdx.x, lane = tid & 63;
    const int wv = tid >> 6, wm = wv >> 1, wn = wv & 1;
    const int colBase = blockIdx.x * 128;

    float bacc[4][8];
#pragma unroll
    for (int it = 0; it < 4; ++it)
#pragma unroll
        for (int j = 0; j < 8; ++j) bacc[it][j] = 0.f;

    for (int head = 0; head < NHEADS; ++head) {
        if (head) __syncthreads();
#pragma unroll
        for (int it = 0; it < 4; ++it) {
            const int c = it * 256 + tid;
            const int kg = c & 7, idx = c >> 3;
            const int slot = kg * 128 + (idx ^ kg);
            const half8_t xv = *(const half8_t*)(xt + (long)(colBase + idx) * CDIM + head * 64 + kg * 8);
            half8_t bv;
#pragma unroll
            for (int j = 0; j < 8; ++j) { bacc[it][j] += (float)xv[j]; bv[j] = (_Float16)bacc[it][j]; }
            *(half8_t*)(Bs + slot * 8) = bv;
            const half8_t av = *(const half8_t*)(vsw + (long)head * (C4 * 64) + idx * 64 + kg * 8);
            *(half8_t*)(As + slot * 8) = av;
        }
        __syncthreads();

        f32x4_t acc[4][4];
#pragma unroll
        for (int i = 0; i < 4; ++i)
#pragma unroll
            for (int j = 0; j < 4; ++j) acc[i][j] = (f32x4_t){0.f, 0.f, 0.f, 0.f};
#pragma unroll
        for (int ks = 0; ks < 2; ++ks) {
            const int kg = ks * 4 + (lane >> 4);
            half8_t a[4], b[4];
#pragma unroll
            for (int mf = 0; mf < 4; ++mf) {
                const int idx = wm * 64 + mf * 16 + (lane & 15);
                a[mf] = *(const half8_t*)(As + (kg * 128 + (idx ^ kg)) * 8);
            }
#pragma unroll
            for (int nf = 0; nf < 4; ++nf) {
                const int idx = wn * 64 + nf * 16 + (lane & 15);
                b[nf] = *(const half8_t*)(Bs + (kg * 128 + (idx ^ kg)) * 8);
            }
#pragma unroll
            for (int mf = 0; mf < 4; ++mf)
#pragma unroll
                for (int nf = 0; nf < 4; ++nf)
                    acc[mf][nf] = __builtin_amdgcn_mfma_f32_16x16x32_f16(a[mf], b[nf], acc[mf][nf], 0, 0, 0);
        }

        const int rbase = wm * 64 + (lane >> 4) * 4;
        const int cbase = colBase + wn * 64 + (lane & 15);
        const float* bnh = vsbn + head * 4 * C4;
#pragma unroll
        for (int mf = 0; mf < 4; ++mf) {
            const int o0 = rbase + mf * 16;
            float inv[4], add[4];
#pragma unroll
            for (int j = 0; j < 4; ++j) bn_coef(bnh, C4, o0 + j, inv[j], add[j]);
#pragma unroll
            for (int nf = 0; nf < 4; ++nf) {
                const int col = cbase + nf * 16;
                _Float16* dst = concat_t + (long)col * CCAT + head * C4 + o0;
                half4_t v;
#pragma unroll
                for (int j = 0; j < 4; ++j) v[j] = (_Float16)(acc[mf][nf][j] * inv[j] + add[j]);
                *(half4_t*)dst = v;
            }
        }
    }
}

// ---- depthwise 5x5 SAME + BN; feat_t [sp][256] (q = c<128) -> qdw_t [sp][128] ----
__global__ __launch_bounds__(256)
void dwconv_t_kernel(const _Float16* __restrict__ feat_t, const float* __restrict__ dww,
                     const float* __restrict__ dwbn, _Float16* __restrict__ qdw_t)
{
    const int h = blockIdx.x, b = blockIdx.y, ch0 = blockIdx.z * 64;
    __shared__ _Float16 rows[5][32][64];  // [dy][iw+2][c], borders zero
    for (int i = threadIdx.x; i < 5 * 32 * 64; i += 256) {
        const int dy = i / (32 * 64);
        const int rem = i - dy * (32 * 64);
        const int iw = rem >> 6, c = rem & 63;
        const int ih = h + dy - 2, w = iw - 2;
        _Float16 v = (_Float16)0.f;
        if (ih >= 0 && ih < 28 && w >= 0 && w < 28)
            v = feat_t[((long)b * NSP + ih * 28 + w) * CQK + ch0 + c];
        rows[dy][iw][c] = v;
    }
    const int pr = threadIdx.x & 31;          // channel pair, fixed per thread
    const int c2 = pr * 2;
    float wr0[25], wr1[25];
#pragma unroll
    for (int q = 0; q < 25; ++q) {
        wr0[q] = dww[(ch0 + c2) * 25 + q];
        wr1[q] = dww[(ch0 + c2 + 1) * 25 + q];
    }
    float inv0, add0, inv1, add1;
    bn_coef(dwbn, C4, ch0 + c2, inv0, add0);
    bn_coef(dwbn, C4, ch0 + c2 + 1, inv1, add1);
    __syncthreads();
    for (int l = threadIdx.x; l < 28 * 32; l += 256) {
        const int w = l >> 5;
        float a0 = 0.f, a1 = 0.f;
#pragma unroll
        for (int dy = 0; dy < 5; ++dy)
#pragma unroll
            for (int dx = 0; dx < 5; ++dx) {
                const half2_t v2 = *(const half2_t*)(&rows[dy][w + dx][c2]);
                a0 += wr0[dy * 5 + dx] * (float)v2[0];
                a1 += wr1[dy * 5 + dx] * (float)v2[1];
            }
        half2_t o2; o2[0] = (_Float16)(a0 * inv0 + add0); o2[1] = (_Float16)(a1 * inv1 + add1);
        *(half2_t*)(qdw_t + ((long)b * NSP + h * 28 + w) * C4 + ch0 + c2) = o2;
    }
}

// ---- attention maps. ROWMODE: fix=h, positions w (bias_w). else fix=w, positions h (bias_h). ----
template<bool ROWMODE>
__global__ __launch_bounds__(256)
void attn_map_kernel(const _Float16* __restrict__ qdw_t, const _Float16* __restrict__ feat_t,
                     const float* __restrict__ biasv, float* __restrict__ attn_out)
{
    const int fix = blockIdx.x, b = blockIdx.y;
    __shared__ _Float16 Qs[28][136];
    __shared__ _Float16 Ks[28][136];
    __shared__ float S[28][28];
    __shared__ float bsh[28];
    if (threadIdx.x < 28) bsh[threadIdx.x] = biasv[threadIdx.x];
    for (int l = threadIdx.x; l < 28 * 16; l += 256) {
        const int p = l >> 4, c8 = (l & 15) * 8;
        const int sp = ROWMODE ? (fix * 28 + p) : (p * 28 + fix);
        *(half8_t*)(&Qs[p][c8]) = *(const half8_t*)(qdw_t + ((long)b * NSP + sp) * C4 + c8);
        *(half8_t*)(&Ks[p][c8]) = *(const half8_t*)(feat_t + ((long)b * NSP + sp) * CQK + 128 + c8);
    }
    __syncthreads();
    for (int e = threadIdx.x; e < 784; e += 256) {
        const int qp = e / 28, kp = e - (e / 28) * 28;
        float acc = 0.f;
        const half2_t* qv = (const half2_t*)&Qs[qp][0];
        const half2_t* kv = (const half2_t*)&Ks[kp][0];
#pragma unroll
        for (int c = 0; c < 64; ++c) acc = fdot2(qv[c], kv[c], acc);
        const int dd = qp - kp;
        S[qp][kp] = acc * ATT_SCALE + bsh[dd < 0 ? -dd : dd];
    }
    __syncthreads();
    const int r = threadIdx.x >> 3, g = threadIdx.x & 7;
    if (r < 28) {
        float mx = -1e30f;
#pragma unroll
        for (int j = 0; j < 4; ++j) { const int k = g + j * 8; if (k < 28) mx = fmaxf(mx, S[r][k]); }
        mx = fmaxf(mx, __shfl_xor(mx, 1));
        mx = fmaxf(mx, __shfl_xor(mx, 2));
        mx = fmaxf(mx, __shfl_xor(mx, 4));
        float e4[4], sum = 0.f;
#pragma unroll
        for (int j = 0; j < 4; ++j) {
            const int k = g + j * 8;
            e4[j] = (k < 28) ? __expf(S[r][k] - mx) : 0.f;
            sum += e4[j];
        }
        sum += __shfl_xor(sum, 1);
        sum += __shfl_xor(sum, 2);
        sum += __shfl_xor(sum, 4);
        const float rinv = 1.f / sum;
        float* dst = attn_out + (((long)b * 28 + fix) * 28 + r) * 28;
#pragma unroll
        for (int j = 0; j < 4; ++j) { const int k = g + j * 8; if (k < 28) dst[k] = e4[j] * rinv; }
    }
}

// ---- MFMA attention apply, in place on concat_t, batched over all 1024 channels. ----
// STAGE2=0: block (k-row r, b): M1[sp=r*28+w][d] = sum_j attw[b,r][w][j] * V[sp=r*28+j][d]
// STAGE2=1: block (w-col r, b): out[sp=h*28+r][d] = relu(sum_k atth[b,r][h][k] * M1[sp=k*28+r][d])
// Formulation D[d][col]: A-operand = V^T (LDS-transposed), B-operand = attn matrix (row-major).
__global__ __launch_bounds__(256)
void attn_apply_kernel(_Float16* __restrict__ concat_t, const float* __restrict__ attn,
                       int stage2)
{
    const int r = blockIdx.x, b = blockIdx.y;
    __shared__ _Float16 Vs[28][1026];   // linear rows, odd-dword stride (conflict-free)
    __shared__ _Float16 Vt[256][34];    // transposed quarter, 17-dword stride
    __shared__ _Float16 Bs[32][36];     // attn matrix, K-padded with zeros
    const int tid = threadIdx.x, lane = tid & 63, wv = tid >> 6;
    const int kg = lane >> 4, lr = lane & 15;

    const float* amat = attn + ((long)b * 28 + r) * 784;
    for (int i = tid; i < 32 * 36; i += 256) {
        const int w = i / 36, j = i - w * 36;
        Bs[w][j] = (w < 28 && j < 28) ? (_Float16)amat[w * 28 + j] : (_Float16)0.f;
    }
    _Float16* cbase = concat_t + (long)b * NSP * CCAT;
#pragma unroll
    for (int it = 0; it < 14; ++it) {
        const int task = it * 256 + tid;
        const int j = task >> 7, d8 = task & 127;
        const int sp = stage2 ? (j * 28 + r) : (r * 28 + j);
        *(half8_t*)(&Vs[j][d8 * 8]) = *(const half8_t*)(cbase + (long)sp * CCAT + d8 * 8);
    }
    __syncthreads();

    const half8_t bf0 = *(const half8_t*)(&Bs[lr][kg * 8]);
    const half8_t bf1 = *(const half8_t*)(&Bs[16 + lr][kg * 8]);

    for (int qd = 0; qd < 4; ++qd) {
        if (qd) __syncthreads();
        // transpose quarter qd (d = qd*256 .. +255) into Vt; zero K-pad rows
        for (int i = tid; i < 1024; i += 256) {
            const int j = i & 31, d8q = i >> 5;
            if (j < 28) {
                const half8_t v = *(const half8_t*)(&Vs[j][(qd * 32 + d8q) * 8]);
#pragma unroll
                for (int q = 0; q < 8; ++q) Vt[d8q * 8 + q][j] = v[q];
            } else {
#pragma unroll
                for (int q = 0; q < 8; ++q) Vt[d8q * 8 + q][j] = (_Float16)0.f;
            }
        }
        __syncthreads();
#pragma unroll
        for (int mq = 0; mq < 4; ++mq) {
            const int mt = wv * 4 + mq;
            const half8_t af = *(const half8_t*)(&Vt[mt * 16 + lr][kg * 8]);
            f32x4_t acc0 = (f32x4_t){0.f, 0.f, 0.f, 0.f};
            f32x4_t acc1 = (f32x4_t){0.f, 0.f, 0.f, 0.f};
            acc0 = __builtin_amdgcn_mfma_f32_16x16x32_f16(af, bf0, acc0, 0, 0, 0);
            acc1 = __builtin_amdgcn_mfma_f32_16x16x32_f16(af, bf1, acc1, 0, 0, 0);
            const int d0 = qd * 256 + mt * 16 + kg * 4;
            {
                const int col = lr;
                const int sp = stage2 ? (col * 28 + r) : (r * 28 + col);
                half4_t v;
#pragma unroll
                for (int q = 0; q < 4; ++q) {
                    float xv = acc0[q];
                    if (stage2) xv = fmaxf(xv, 0.f);
                    v[q] = (_Float16)xv;
                }
                *(half4_t*)(cbase + (long)sp * CCAT + d0) = v;
            }
            if (16 + lr < 28) {
                const int col = 16 + lr;
                const int sp = stage2 ? (col * 28 + r) : (r * 28 + col);
                half4_t v;
#pragma unroll
                for (int q = 0; q < 4; ++q) {
                    float xv = acc1[q];
                    if (stage2) xv = fmaxf(xv, 0.f);
                    v[q] = (_Float16)xv;
                }
                *(half4_t*)(cbase + (long)sp * CCAT + d0) = v;
            }
        }
    }
}

extern "C" void kernel_launch(void* const* d_in, const int* in_sizes, int n_in,
                              void* d_out, int out_size, void* d_ws, size_t ws_size,
                              hipStream_t stream)
{
    const float* x        = (const float*)d_in[0];
    const float* qk_w     = (const float*)d_in[1];
    const float* qk_bn    = (const float*)d_in[2];
    const float* dws_w    = (const float*)d_in[3];
    const float* dws_bn   = (const float*)d_in[4];
    const float* vs_w     = (const float*)d_in[5];
    const float* vs_bn    = (const float*)d_in[6];
    const float* proj_w   = (const float*)d_in[7];
    const float* proj_bn  = (const float*)d_in[8];
    const float* bias_h   = (const float*)d_in[9];
    const float* bias_w   = (const float*)d_in[10];

    // --- scratch inside d_out (fully overwritten by proj GEMM at the end) ---
    char* ob = (char*)d_out;
    _Float16* x_t    = (_Float16*)ob;                    // 51,380,224 B
    float*    attw   = (float*)(ob + 51380224);          //  5,619,712 B
    float*    atth   = (float*)(ob + 56999936);          //  5,619,712 B -> 62,619,648
    _Float16* feat_t = (_Float16*)(ob + 62619648);       // 25,690,112 B -> 88,309,760
    _Float16* qdw_t  = (_Float16*)(ob + 88309760);       // 12,845,056 B -> 101,154,816

    // --- ws: concat_t + f16 weights ---
    _Float16* concat_t = (_Float16*)d_ws;                           // 102,760,448 B
    _Float16* w_h      = (_Float16*)((char*)d_ws + 102760448);      // 1,441,792 B
    _Float16* qk_w_h   = w_h;
    _Float16* vs_w_h   = w_h + 131072;
    _Float16* proj_w_h = w_h + 196608;

    transpose_x_kernel<<<dim3(16, NB), 256, 0, stream>>>(x, x_t);
    convert_w_kernel<<<704, 256, 0, stream>>>(qk_w, vs_w, proj_w, w_h);

    // feat_t = BN(qk_w @ x)   [sp][256] f16
    mfma_gemm_kernel<CDIM, true><<<dim3(392, 2), 256, 0, stream>>>(
        x_t, qk_w_h, qk_bn, feat_t, CQK);
    dwconv_t_kernel<<<dim3(28, NB, 2), 256, 0, stream>>>(feat_t, dws_w, dws_bn, qdw_t);
    attn_map_kernel<true><<<dim3(28, NB), 256, 0, stream>>>(qdw_t, feat_t, bias_w, attw);
    attn_map_kernel<false><<<dim3(28, NB), 256, 0, stream>>>(qdw_t, feat_t, bias_h, atth);

    // all-heads V GEMM with on-the-fly prefix-summed cascade input
    vall_kernel<<<392, 256, 0, stream>>>(x_t, vs_w_h, vs_bn, concat_t);

    // attention applies (MFMA), batched over all channels, in place on concat_t
    attn_apply_kernel<<<dim3(28, NB), 256, 0, stream>>>(concat_t, attw, 0);
    attn_apply_kernel<<<dim3(28, NB), 256, 0, stream>>>(concat_t, atth, 1);

    // out = BN(proj_w @ relu(concat))  (relu folded into stage2)
    mfma_gemm_kernel<CCAT, false><<<dim3(392, 4), 256, 0, stream>>>(
        concat_t, proj_w_h, proj_bn, (float*)d_out, CDIM);
}

// Round 5
// 416.805 us; speedup vs baseline: 4.2215x; 1.0498x over previous
//
#include <hip/hip_runtime.h>
#include <hip/hip_fp16.h>

#define NB 64
#define NSP 784
#define CDIM 512
#define CQK 256
#define C4 128
#define NHEADS 8
#define CCAT 1024
#define BN_EPS 1e-5f
#define ATT_SCALE 0.17677669529663687f  // 32^-0.5

using half8_t = __attribute__((ext_vector_type(8))) _Float16;
using half4_t = __attribute__((ext_vector_type(4))) _Float16;
using half2_t = __attribute__((ext_vector_type(2))) _Float16;
using f32x4_t = __attribute__((ext_vector_type(4))) float;

__device__ __forceinline__ void bn_coef(const float* bn, int cout, int o, float& inv, float& add) {
    float g = bn[o], be = bn[cout + o], m = bn[2 * cout + o], v = bn[3 * cout + o];
    inv = g * rsqrtf(v + BN_EPS);
    add = be - m * inv;
}

__device__ __forceinline__ float fdot2(half2_t a, half2_t b, float c) {
#if __has_builtin(__builtin_amdgcn_fdot2)
    return __builtin_amdgcn_fdot2(a, b, c, false);
#else
    return c + (float)a[0] * (float)b[0] + (float)a[1] * (float)b[1];
#endif
}

// async global->LDS, 16B per lane; LDS dest must be wave-linear (base + lane*16).
__device__ __forceinline__ void gload16(const void* g, void* l) {
    __builtin_amdgcn_global_load_lds(
        (const __attribute__((address_space(1))) void*)g,
        (__attribute__((address_space(3))) void*)l, 16, 0, 0);
}

// ---- x [64][512][784] f32 -> x_t [64*784][512] f16 ----
__global__ __launch_bounds__(256)
void transpose_x_kernel(const float* __restrict__ x, _Float16* __restrict__ xt)
{
    __shared__ _Float16 t[32 * 786];
    const int b = blockIdx.y, c0 = blockIdx.x * 32;
    const float* src = x + ((long)b * CDIM + c0) * NSP;
    for (int i = threadIdx.x; i < 32 * NSP; i += 256) {
        const int c = i / NSP, sp = i - c * NSP;
        t[c * 786 + sp] = (_Float16)src[i];
    }
    __syncthreads();
    _Float16* dst = xt + (long)b * NSP * CDIM + c0;
    for (int sp = threadIdx.x; sp < NSP; sp += 256) {
        half8_t* d8 = (half8_t*)(dst + (long)sp * CDIM);
#pragma unroll
        for (int q = 0; q < 4; ++q) {
            half8_t v;
#pragma unroll
            for (int j = 0; j < 8; ++j) v[j] = t[(q * 8 + j) * 786 + sp];
            d8[q] = v;
        }
    }
}

// ---- convert qk_w (131072) + vs_w (65536) + proj_w (524288) f32 -> f16 ----
__global__ __launch_bounds__(256)
void convert_w_kernel(const float* __restrict__ qk, const float* __restrict__ vs,
                      const float* __restrict__ pj, _Float16* __restrict__ dst)
{
    const int e = (blockIdx.x * 256 + threadIdx.x) * 4;
    const float* src; int off; _Float16* d;
    if (e < 131072)      { src = qk; off = e;          d = dst; }
    else if (e < 196608) { src = vs; off = e - 131072; d = dst + 131072; }
    else                 { src = pj; off = e - 196608; d = dst + 196608; }
    const float4 v = *(const float4*)(src + off);
    half4_t h; h[0] = (_Float16)v.x; h[1] = (_Float16)v.y; h[2] = (_Float16)v.z; h[3] = (_Float16)v.w;
    *(half4_t*)(d + off) = h;
}

// ---- MFMA GEMM: Out[o][col] = BN(sum_k W[o][k] * InT[col][k]) ----
// 128x128 tile, BK=64, 4 waves (2x2), 16x16x32 f16 MFMA.
// LDS layout linear [idx][kg] (slot = idx*8+kg), staged via global_load_lds.
// Grid: 1D, o-tile fastest + bijective XCD swizzle (gridDim.x % 8 == 0).
template<int CIN, int NT, bool OUT_T>
__global__ __launch_bounds__(256)
void mfma_gemm_kernel(const _Float16* __restrict__ inH, const _Float16* __restrict__ wA,
                      const float* __restrict__ bnp, void* __restrict__ outp, int cout)
{
    __shared__ _Float16 As[8192];
    __shared__ _Float16 Bs[8192];
    const int tid = threadIdx.x;
    const int lane = tid & 63;
    const int wv = tid >> 6;
    const int wm = wv >> 1, wn = wv & 1;
    const int grp = gridDim.x >> 3;
    const int tile = (blockIdx.x & 7) * grp + (blockIdx.x >> 3);
    const int oBase = (tile % NT) * 128;
    const int colBase = (tile / NT) * 128;

    f32x4_t acc[4][4];
#pragma unroll
    for (int i = 0; i < 4; ++i)
#pragma unroll
        for (int j = 0; j < 4; ++j) acc[i][j] = (f32x4_t){0.f, 0.f, 0.f, 0.f};

    for (int k0 = 0; k0 < CIN; k0 += 64) {
        if (k0) __syncthreads();
#pragma unroll
        for (int it = 0; it < 4; ++it) {
            const int s = it * 256 + tid;
            const int sidx = s >> 3, skg = s & 7;
            gload16(wA + (long)(oBase + sidx) * CIN + k0 + skg * 8, As + s * 8);
            gload16(inH + (long)(colBase + sidx) * CIN + k0 + skg * 8, Bs + s * 8);
        }
        __syncthreads();
#pragma unroll
        for (int ks = 0; ks < 2; ++ks) {
            const int kq = ks * 4 + (lane >> 4);
            half8_t a[4], b[4];
#pragma unroll
            for (int mf = 0; mf < 4; ++mf) {
                const int idx = wm * 64 + mf * 16 + (lane & 15);
                a[mf] = *(const half8_t*)(As + (idx * 8 + kq) * 8);
            }
#pragma unroll
            for (int nf = 0; nf < 4; ++nf) {
                const int idx = wn * 64 + nf * 16 + (lane & 15);
                b[nf] = *(const half8_t*)(Bs + (idx * 8 + kq) * 8);
            }
#pragma unroll
            for (int mf = 0; mf < 4; ++mf)
#pragma unroll
                for (int nf = 0; nf < 4; ++nf)
                    acc[mf][nf] = __builtin_amdgcn_mfma_f32_16x16x32_f16(a[mf], b[nf], acc[mf][nf], 0, 0, 0);
        }
    }

    const int rbase = wm * 64 + (lane >> 4) * 4;
    const int cbase = colBase + wn * 64 + (lane & 15);
#pragma unroll
    for (int mf = 0; mf < 4; ++mf) {
        const int o0 = oBase + rbase + mf * 16;
        float inv[4], add[4];
#pragma unroll
        for (int j = 0; j < 4; ++j) bn_coef(bnp, cout, o0 + j, inv[j], add[j]);
#pragma unroll
        for (int nf = 0; nf < 4; ++nf) {
            const int col = cbase + nf * 16;
            if constexpr (OUT_T) {
                _Float16* dst = (_Float16*)outp + (long)col * cout + o0;
                half4_t v;
#pragma unroll
                for (int j = 0; j < 4; ++j) v[j] = (_Float16)(acc[mf][nf][j] * inv[j] + add[j]);
                *(half4_t*)dst = v;
            } else {
                const int bb = col / NSP, sp = col - bb * NSP;
                float* dst = (float*)outp + ((long)bb * cout + o0) * NSP + sp;
#pragma unroll
                for (int j = 0; j < 4; ++j) dst[(long)j * NSP] = acc[mf][nf][j] * inv[j] + add[j];
            }
        }
    }
}

// ---- vall: per 128-col tile, prefix-sum x_t slices in f32 regs; per head MFMA with
//      W_h and write BN'd f16 into concat_t[col][head*128+o]. ----
__global__ __launch_bounds__(256)
void vall_kernel(const _Float16* __restrict__ xt, const _Float16* __restrict__ vsw,
                 const float* __restrict__ vsbn, _Float16* __restrict__ concat_t)
{
    __shared__ _Float16 As[8192];
    __shared__ _Float16 Bs[8192];
    const int tid = threadIdx.x, lane = tid & 63;
    const int wv = tid >> 6, wm = wv >> 1, wn = wv & 1;
    const int colBase = blockIdx.x * 128;

    float bacc[4][8];
#pragma unroll
    for (int it = 0; it < 4; ++it)
#pragma unroll
        for (int j = 0; j < 8; ++j) bacc[it][j] = 0.f;

    for (int head = 0; head < NHEADS; ++head) {
        if (head) __syncthreads();
#pragma unroll
        for (int it = 0; it < 4; ++it) {
            const int c = it * 256 + tid;
            const int kg = c & 7, idx = c >> 3;
            const half8_t xv = *(const half8_t*)(xt + (long)(colBase + idx) * CDIM + head * 64 + kg * 8);
            half8_t bv;
#pragma unroll
            for (int j = 0; j < 8; ++j) { bacc[it][j] += (float)xv[j]; bv[j] = (_Float16)bacc[it][j]; }
            *(half8_t*)(Bs + c * 8) = bv;
            gload16(vsw + (long)head * (C4 * 64) + idx * 64 + kg * 8, As + c * 8);
        }
        __syncthreads();

        f32x4_t acc[4][4];
#pragma unroll
        for (int i = 0; i < 4; ++i)
#pragma unroll
            for (int j = 0; j < 4; ++j) acc[i][j] = (f32x4_t){0.f, 0.f, 0.f, 0.f};
#pragma unroll
        for (int ks = 0; ks < 2; ++ks) {
            const int kq = ks * 4 + (lane >> 4);
            half8_t a[4], b[4];
#pragma unroll
            for (int mf = 0; mf < 4; ++mf) {
                const int idx = wm * 64 + mf * 16 + (lane & 15);
                a[mf] = *(const half8_t*)(As + (idx * 8 + kq) * 8);
            }
#pragma unroll
            for (int nf = 0; nf < 4; ++nf) {
                const int idx = wn * 64 + nf * 16 + (lane & 15);
                b[nf] = *(const half8_t*)(Bs + (idx * 8 + kq) * 8);
            }
#pragma unroll
            for (int mf = 0; mf < 4; ++mf)
#pragma unroll
                for (int nf = 0; nf < 4; ++nf)
                    acc[mf][nf] = __builtin_amdgcn_mfma_f32_16x16x32_f16(a[mf], b[nf], acc[mf][nf], 0, 0, 0);
        }

        const int rbase = wm * 64 + (lane >> 4) * 4;
        const int cbase = colBase + wn * 64 + (lane & 15);
        const float* bnh = vsbn + head * 4 * C4;
#pragma unroll
        for (int mf = 0; mf < 4; ++mf) {
            const int o0 = rbase + mf * 16;
            float inv[4], add[4];
#pragma unroll
            for (int j = 0; j < 4; ++j) bn_coef(bnh, C4, o0 + j, inv[j], add[j]);
#pragma unroll
            for (int nf = 0; nf < 4; ++nf) {
                const int col = cbase + nf * 16;
                _Float16* dst = concat_t + (long)col * CCAT + head * C4 + o0;
                half4_t v;
#pragma unroll
                for (int j = 0; j < 4; ++j) v[j] = (_Float16)(acc[mf][nf][j] * inv[j] + add[j]);
                *(half4_t*)dst = v;
            }
        }
    }
}

// ---- depthwise 5x5 SAME + BN; feat_t [sp][256] (q = c<128) -> qdw_t [sp][128] ----
__global__ __launch_bounds__(256)
void dwconv_t_kernel(const _Float16* __restrict__ feat_t, const float* __restrict__ dww,
                     const float* __restrict__ dwbn, _Float16* __restrict__ qdw_t)
{
    const int h = blockIdx.x, b = blockIdx.y, ch0 = blockIdx.z * 64;
    __shared__ _Float16 rows[5][32][64];  // [dy][iw+2][c], borders zero
    for (int i = threadIdx.x; i < 5 * 32 * 64; i += 256) {
        const int dy = i / (32 * 64);
        const int rem = i - dy * (32 * 64);
        const int iw = rem >> 6, c = rem & 63;
        const int ih = h + dy - 2, w = iw - 2;
        _Float16 v = (_Float16)0.f;
        if (ih >= 0 && ih < 28 && w >= 0 && w < 28)
            v = feat_t[((long)b * NSP + ih * 28 + w) * CQK + ch0 + c];
        rows[dy][iw][c] = v;
    }
    const int pr = threadIdx.x & 31;
    const int c2 = pr * 2;
    float wr0[25], wr1[25];
#pragma unroll
    for (int q = 0; q < 25; ++q) {
        wr0[q] = dww[(ch0 + c2) * 25 + q];
        wr1[q] = dww[(ch0 + c2 + 1) * 25 + q];
    }
    float inv0, add0, inv1, add1;
    bn_coef(dwbn, C4, ch0 + c2, inv0, add0);
    bn_coef(dwbn, C4, ch0 + c2 + 1, inv1, add1);
    __syncthreads();
    for (int l = threadIdx.x; l < 28 * 32; l += 256) {
        const int w = l >> 5;
        float a0 = 0.f, a1 = 0.f;
#pragma unroll
        for (int dy = 0; dy < 5; ++dy)
#pragma unroll
            for (int dx = 0; dx < 5; ++dx) {
                const half2_t v2 = *(const half2_t*)(&rows[dy][w + dx][c2]);
                a0 += wr0[dy * 5 + dx] * (float)v2[0];
                a1 += wr1[dy * 5 + dx] * (float)v2[1];
            }
        half2_t o2; o2[0] = (_Float16)(a0 * inv0 + add0); o2[1] = (_Float16)(a1 * inv1 + add1);
        *(half2_t*)(qdw_t + ((long)b * NSP + h * 28 + w) * C4 + ch0 + c2) = o2;
    }
}

// ---- attention maps -> padded f16 [b][28 fix][32 q][32 k], zero-filled pads. ----
template<bool ROWMODE>
__global__ __launch_bounds__(256)
void attn_map_kernel(const _Float16* __restrict__ qdw_t, const _Float16* __restrict__ feat_t,
                     const float* __restrict__ biasv, _Float16* __restrict__ attn_out)
{
    const int fix = blockIdx.x, b = blockIdx.y;
    __shared__ _Float16 Qs[28][136];
    __shared__ _Float16 Ks[28][136];
    __shared__ float S[28][28];
    __shared__ float bsh[28];
    if (threadIdx.x < 28) bsh[threadIdx.x] = biasv[threadIdx.x];
    for (int l = threadIdx.x; l < 28 * 16; l += 256) {
        const int p = l >> 4, c8 = (l & 15) * 8;
        const int sp = ROWMODE ? (fix * 28 + p) : (p * 28 + fix);
        *(half8_t*)(&Qs[p][c8]) = *(const half8_t*)(qdw_t + ((long)b * NSP + sp) * C4 + c8);
        *(half8_t*)(&Ks[p][c8]) = *(const half8_t*)(feat_t + ((long)b * NSP + sp) * CQK + 128 + c8);
    }
    __syncthreads();
    for (int e = threadIdx.x; e < 784; e += 256) {
        const int qp = e / 28, kp = e - (e / 28) * 28;
        float acc = 0.f;
        const half2_t* qv = (const half2_t*)&Qs[qp][0];
        const half2_t* kv = (const half2_t*)&Ks[kp][0];
#pragma unroll
        for (int c = 0; c < 64; ++c) acc = fdot2(qv[c], kv[c], acc);
        const int dd = qp - kp;
        S[qp][kp] = acc * ATT_SCALE + bsh[dd < 0 ? -dd : dd];
    }
    __syncthreads();
    const int r = threadIdx.x >> 3, g = threadIdx.x & 7;
    if (r < 28) {
        float mx = -1e30f;
#pragma unroll
        for (int j = 0; j < 4; ++j) { const int k = g + j * 8; if (k < 28) mx = fmaxf(mx, S[r][k]); }
        mx = fmaxf(mx, __shfl_xor(mx, 1));
        mx = fmaxf(mx, __shfl_xor(mx, 2));
        mx = fmaxf(mx, __shfl_xor(mx, 4));
        float e4[4], sum = 0.f;
#pragma unroll
        for (int j = 0; j < 4; ++j) {
            const int k = g + j * 8;
            e4[j] = (k < 28) ? __expf(S[r][k] - mx) : 0.f;
            sum += e4[j];
        }
        sum += __shfl_xor(sum, 1);
        sum += __shfl_xor(sum, 2);
        sum += __shfl_xor(sum, 4);
        const float rinv = 1.f / sum;
#pragma unroll
        for (int j = 0; j < 4; ++j) { const int k = g + j * 8; if (k < 28) S[r][k] = e4[j] * rinv; }
    }
    __syncthreads();
    _Float16* dst = attn_out + ((long)b * 28 + fix) * 1024;
    for (int i = threadIdx.x; i < 1024; i += 256) {
        const int q = i >> 5, k = i & 31;
        dst[i] = (q < 28 && k < 28) ? (_Float16)S[q][k] : (_Float16)0.f;
    }
}

// ---- fused row+col attention apply + ReLU, in place on concat_t. ----
// Block = (dq of 32 channels, b), 512 threads / 8 waves.
// V LDS: (d, r, j) at d*904 + r*32 + j (d-major, j-contiguous for stage1 A).
// M1 LDS: (w, d, k) at (w*33 + d)*40 + k (k-contiguous for stage2 A).
__global__ __launch_bounds__(512)
void fused_stage_kernel(_Float16* __restrict__ concat_t,
                        const _Float16* __restrict__ attw,
                        const _Float16* __restrict__ atth)
{
    const int dq = blockIdx.x, b = blockIdx.y;
    __shared__ _Float16 V[32 * 904];
    __shared__ _Float16 M1[28 * 33 * 40];
    const int tid = threadIdx.x, lane = tid & 63, wv = tid >> 6;
    const int kg = lane >> 4, lr = lane & 15;

    _Float16* cbase = concat_t + (long)b * NSP * CCAT + dq * 32;

    // zero K-pads
    for (int p = tid; p < 32 * 28 * 4; p += 512) {
        const int d = p / 112, rem = p - d * 112;
        V[d * 904 + (rem >> 2) * 32 + 28 + (rem & 3)] = (_Float16)0.f;
    }
    for (int p = tid; p < 28 * 33 * 4; p += 512) {
        M1[(p >> 2) * 40 + 28 + (p & 3)] = (_Float16)0.f;
    }
    // load V chunk (transpose to d-major)
    for (int t = tid; t < 3136; t += 512) {
        const int sp = t >> 2, c0 = (t & 3) * 8;
        const int r = sp / 28, j = sp - r * 28;
        const half8_t v = *(const half8_t*)(cbase + (long)sp * CCAT + c0);
#pragma unroll
        for (int q = 0; q < 8; ++q) V[(c0 + q) * 904 + r * 32 + j] = v[q];
    }
    __syncthreads();

    // stage 1: rows r; D1[d][w] = sum_j V[d][r][j] * attw[b][r][w][j]
    for (int r = wv; r < 28; r += 8) {
        const _Float16* bw = attw + ((long)b * 28 + r) * 1024;
        half8_t a0 = *(const half8_t*)(V + lr * 904 + r * 32 + kg * 8);
        half8_t a1 = *(const half8_t*)(V + (16 + lr) * 904 + r * 32 + kg * 8);
        half8_t b0 = *(const half8_t*)(bw + lr * 32 + kg * 8);
        half8_t b1 = *(const half8_t*)(bw + (16 + lr) * 32 + kg * 8);
        f32x4_t acc[2][2];
#pragma unroll
        for (int i = 0; i < 2; ++i)
#pragma unroll
            for (int j = 0; j < 2; ++j) acc[i][j] = (f32x4_t){0.f, 0.f, 0.f, 0.f};
        acc[0][0] = __builtin_amdgcn_mfma_f32_16x16x32_f16(a0, b0, acc[0][0], 0, 0, 0);
        acc[0][1] = __builtin_amdgcn_mfma_f32_16x16x32_f16(a0, b1, acc[0][1], 0, 0, 0);
        acc[1][0] = __builtin_amdgcn_mfma_f32_16x16x32_f16(a1, b0, acc[1][0], 0, 0, 0);
        acc[1][1] = __builtin_amdgcn_mfma_f32_16x16x32_f16(a1, b1, acc[1][1], 0, 0, 0);
#pragma unroll
        for (int mt = 0; mt < 2; ++mt)
#pragma unroll
            for (int nt = 0; nt < 2; ++nt) {
                const int w = nt * 16 + lr;
                if (w < 28) {
                    const int dbase = mt * 16 + kg * 4;
#pragma unroll
                    for (int q = 0; q < 4; ++q)
                        M1[(w * 33 + dbase + q) * 40 + r] = (_Float16)acc[mt][nt][q];
                }
            }
    }
    __syncthreads();

    // stage 2: cols w; D2[d][h] = sum_k M1[w][d][k] * atth[b][w][h][k]; relu; write global
    for (int w = wv; w < 28; w += 8) {
        const _Float16* bh = atth + ((long)b * 28 + w) * 1024;
        half8_t a0 = *(const half8_t*)(M1 + (w * 33 + lr) * 40 + kg * 8);
        half8_t a1 = *(const half8_t*)(M1 + (w * 33 + 16 + lr) * 40 + kg * 8);
        half8_t b0 = *(const half8_t*)(bh + lr * 32 + kg * 8);
        half8_t b1 = *(const half8_t*)(bh + (16 + lr) * 32 + kg * 8);
        f32x4_t acc[2][2];
#pragma unroll
        for (int i = 0; i < 2; ++i)
#pragma unroll
            for (int j = 0; j < 2; ++j) acc[i][j] = (f32x4_t){0.f, 0.f, 0.f, 0.f};
        acc[0][0] = __builtin_amdgcn_mfma_f32_16x16x32_f16(a0, b0, acc[0][0], 0, 0, 0);
        acc[0][1] = __builtin_amdgcn_mfma_f32_16x16x32_f16(a0, b1, acc[0][1], 0, 0, 0);
        acc[1][0] = __builtin_amdgcn_mfma_f32_16x16x32_f16(a1, b0, acc[1][0], 0, 0, 0);
        acc[1][1] = __builtin_amdgcn_mfma_f32_16x16x32_f16(a1, b1, acc[1][1], 0, 0, 0);
#pragma unroll
        for (int mt = 0; mt < 2; ++mt)
#pragma unroll
            for (int nt = 0; nt < 2; ++nt) {
                const int hh = nt * 16 + lr;
                if (hh < 28) {
                    const int sp = hh * 28 + w;
                    half4_t v;
#pragma unroll
                    for (int q = 0; q < 4; ++q) v[q] = (_Float16)fmaxf(acc[mt][nt][q], 0.f);
                    *(half4_t*)(cbase + (long)sp * CCAT + mt * 16 + kg * 4) = v;
                }
            }
    }
}

extern "C" void kernel_launch(void* const* d_in, const int* in_sizes, int n_in,
                              void* d_out, int out_size, void* d_ws, size_t ws_size,
                              hipStream_t stream)
{
    const float* x        = (const float*)d_in[0];
    const float* qk_w     = (const float*)d_in[1];
    const float* qk_bn    = (const float*)d_in[2];
    const float* dws_w    = (const float*)d_in[3];
    const float* dws_bn   = (const float*)d_in[4];
    const float* vs_w     = (const float*)d_in[5];
    const float* vs_bn    = (const float*)d_in[6];
    const float* proj_w   = (const float*)d_in[7];
    const float* proj_bn  = (const float*)d_in[8];
    const float* bias_h   = (const float*)d_in[9];
    const float* bias_w   = (const float*)d_in[10];

    // --- scratch inside d_out (fully overwritten by proj GEMM at the end) ---
    char* ob = (char*)d_out;
    _Float16* x_t    = (_Float16*)ob;                    // 51,380,224 B
    _Float16* attw_p = (_Float16*)(ob + 51380224);       //  3,670,016 B
    _Float16* atth_p = (_Float16*)(ob + 55050240);       //  3,670,016 B -> 58,720,256
    _Float16* feat_t = (_Float16*)(ob + 58720256);       // 25,690,112 B -> 84,410,368
    _Float16* qdw_t  = (_Float16*)(ob + 84410368);       // 12,845,056 B -> 97,255,424

    // --- ws: concat_t + f16 weights ---
    _Float16* concat_t = (_Float16*)d_ws;                           // 102,760,448 B
    _Float16* w_h      = (_Float16*)((char*)d_ws + 102760448);      // 1,441,792 B
    _Float16* qk_w_h   = w_h;
    _Float16* vs_w_h   = w_h + 131072;
    _Float16* proj_w_h = w_h + 196608;

    transpose_x_kernel<<<dim3(16, NB), 256, 0, stream>>>(x, x_t);
    convert_w_kernel<<<704, 256, 0, stream>>>(qk_w, vs_w, proj_w, w_h);

    // feat_t = BN(qk_w @ x)   [sp][256] f16
    mfma_gemm_kernel<CDIM, 2, true><<<784, 256, 0, stream>>>(
        x_t, qk_w_h, qk_bn, feat_t, CQK);
    dwconv_t_kernel<<<dim3(28, NB, 2), 256, 0, stream>>>(feat_t, dws_w, dws_bn, qdw_t);
    attn_map_kernel<true><<<dim3(28, NB), 256, 0, stream>>>(qdw_t, feat_t, bias_w, attw_p);
    attn_map_kernel<false><<<dim3(28, NB), 256, 0, stream>>>(qdw_t, feat_t, bias_h, atth_p);

    // all-heads V GEMM with on-the-fly prefix-summed cascade input
    vall_kernel<<<392, 256, 0, stream>>>(x_t, vs_w_h, vs_bn, concat_t);

    // fused row+col attention apply + relu, in place on concat_t
    fused_stage_kernel<<<dim3(32, NB), 512, 0, stream>>>(concat_t, attw_p, atth_p);

    // out = BN(proj_w @ relu(concat))
    mfma_gemm_kernel<CCAT, 4, false><<<1568, 256, 0, stream>>>(
        concat_t, proj_w_h, proj_bn, (float*)d_out, CDIM);
}

// Round 6
// 394.356 us; speedup vs baseline: 4.4618x; 1.0569x over previous
//
#include <hip/hip_runtime.h>
#include <hip/hip_fp16.h>

#define NB 64
#define NSP 784
#define CDIM 512
#define CQK 256
#define C4 128
#define NHEADS 8
#define CCAT 1024
#define BN_EPS 1e-5f
#define ATT_SCALE 0.17677669529663687f  // 32^-0.5

using half8_t = __attribute__((ext_vector_type(8))) _Float16;
using half4_t = __attribute__((ext_vector_type(4))) _Float16;
using half2_t = __attribute__((ext_vector_type(2))) _Float16;
using f32x4_t = __attribute__((ext_vector_type(4))) float;

__device__ __forceinline__ void bn_coef(const float* bn, int cout, int o, float& inv, float& add) {
    float g = bn[o], be = bn[cout + o], m = bn[2 * cout + o], v = bn[3 * cout + o];
    inv = g * rsqrtf(v + BN_EPS);
    add = be - m * inv;
}

__device__ __forceinline__ float fdot2(half2_t a, half2_t b, float c) {
#if __has_builtin(__builtin_amdgcn_fdot2)
    return __builtin_amdgcn_fdot2(a, b, c, false);
#else
    return c + (float)a[0] * (float)b[0] + (float)a[1] * (float)b[1];
#endif
}

// async global->LDS, 16B per lane; LDS dest must be wave-linear (base + lane*16).
__device__ __forceinline__ void gload16(const void* g, void* l) {
    __builtin_amdgcn_global_load_lds(
        (const __attribute__((address_space(1))) void*)g,
        (__attribute__((address_space(3))) void*)l, 16, 0, 0);
}

// ---- x [64][512][784] f32 -> x_t [64*784][512] f16 ----
__global__ __launch_bounds__(256)
void transpose_x_kernel(const float* __restrict__ x, _Float16* __restrict__ xt)
{
    __shared__ _Float16 t[32 * 786];
    const int b = blockIdx.y, c0 = blockIdx.x * 32;
    const float* src = x + ((long)b * CDIM + c0) * NSP;
    for (int i = threadIdx.x; i < 32 * NSP; i += 256) {
        const int c = i / NSP, sp = i - c * NSP;
        t[c * 786 + sp] = (_Float16)src[i];
    }
    __syncthreads();
    _Float16* dst = xt + (long)b * NSP * CDIM + c0;
    for (int sp = threadIdx.x; sp < NSP; sp += 256) {
        half8_t* d8 = (half8_t*)(dst + (long)sp * CDIM);
#pragma unroll
        for (int q = 0; q < 4; ++q) {
            half8_t v;
#pragma unroll
            for (int j = 0; j < 8; ++j) v[j] = t[(q * 8 + j) * 786 + sp];
            d8[q] = v;
        }
    }
}

// ---- convert qk_w (131072) + vs_w (65536) + proj_w (524288) f32 -> f16 ----
__global__ __launch_bounds__(256)
void convert_w_kernel(const float* __restrict__ qk, const float* __restrict__ vs,
                      const float* __restrict__ pj, _Float16* __restrict__ dst)
{
    const int e = (blockIdx.x * 256 + threadIdx.x) * 4;
    const float* src; int off; _Float16* d;
    if (e < 131072)      { src = qk; off = e;          d = dst; }
    else if (e < 196608) { src = vs; off = e - 131072; d = dst + 131072; }
    else                 { src = pj; off = e - 196608; d = dst + 196608; }
    const float4 v = *(const float4*)(src + off);
    half4_t h; h[0] = (_Float16)v.x; h[1] = (_Float16)v.y; h[2] = (_Float16)v.z; h[3] = (_Float16)v.w;
    *(half4_t*)(d + off) = h;
}

// ---- MFMA GEMM: Out[o][col] = BN(sum_k W[o][k] * InT[col][k]) ----
// 128x128 tile, BK=64, 4 waves (2x2), 16x16x32 f16 MFMA.
// global_load_lds staging: LDS dest linear in slot s; global source pre-swizzled so
// slot s = idx*8 + (kg ^ (idx&7)) holds (idx,kg). Fragment reads use the same XOR ->
// 16 lanes cover all 32 banks, 2-way only (free).
// Grid: 1D, o-tile fastest + XCD swizzle (gridDim.x % 8 == 0).
template<int CIN, int NT, bool OUT_T>
__global__ __launch_bounds__(256)
void mfma_gemm_kernel(const _Float16* __restrict__ inH, const _Float16* __restrict__ wA,
                      const float* __restrict__ bnp, void* __restrict__ outp, int cout)
{
    __shared__ _Float16 As[8192];
    __shared__ _Float16 Bs[8192];
    const int tid = threadIdx.x;
    const int lane = tid & 63;
    const int wv = tid >> 6;
    const int wm = wv >> 1, wn = wv & 1;
    const int grp = gridDim.x >> 3;
    const int tile = (blockIdx.x & 7) * grp + (blockIdx.x >> 3);
    const int oBase = (tile % NT) * 128;
    const int colBase = (tile / NT) * 128;

    f32x4_t acc[4][4];
#pragma unroll
    for (int i = 0; i < 4; ++i)
#pragma unroll
        for (int j = 0; j < 4; ++j) acc[i][j] = (f32x4_t){0.f, 0.f, 0.f, 0.f};

    for (int k0 = 0; k0 < CIN; k0 += 64) {
        if (k0) __syncthreads();
#pragma unroll
        for (int it = 0; it < 4; ++it) {
            const int s = it * 256 + tid;
            const int sidx = s >> 3;
            const int skg = (s & 7) ^ (sidx & 7);   // inverse swizzle on global source
            gload16(wA + (long)(oBase + sidx) * CIN + k0 + skg * 8, As + s * 8);
            gload16(inH + (long)(colBase + sidx) * CIN + k0 + skg * 8, Bs + s * 8);
        }
        __syncthreads();
#pragma unroll
        for (int ks = 0; ks < 2; ++ks) {
            const int kq = ks * 4 + (lane >> 4);
            half8_t a[4], b[4];
#pragma unroll
            for (int mf = 0; mf < 4; ++mf) {
                const int idx = wm * 64 + mf * 16 + (lane & 15);
                a[mf] = *(const half8_t*)(As + (idx * 8 + (kq ^ (idx & 7))) * 8);
            }
#pragma unroll
            for (int nf = 0; nf < 4; ++nf) {
                const int idx = wn * 64 + nf * 16 + (lane & 15);
                b[nf] = *(const half8_t*)(Bs + (idx * 8 + (kq ^ (idx & 7))) * 8);
            }
#pragma unroll
            for (int mf = 0; mf < 4; ++mf)
#pragma unroll
                for (int nf = 0; nf < 4; ++nf)
                    acc[mf][nf] = __builtin_amdgcn_mfma_f32_16x16x32_f16(a[mf], b[nf], acc[mf][nf], 0, 0, 0);
        }
    }

    const int rbase = wm * 64 + (lane >> 4) * 4;
    const int cbase = colBase + wn * 64 + (lane & 15);
#pragma unroll
    for (int mf = 0; mf < 4; ++mf) {
        const int o0 = oBase + rbase + mf * 16;
        float inv[4], add[4];
#pragma unroll
        for (int j = 0; j < 4; ++j) bn_coef(bnp, cout, o0 + j, inv[j], add[j]);
#pragma unroll
        for (int nf = 0; nf < 4; ++nf) {
            const int col = cbase + nf * 16;
            if constexpr (OUT_T) {
                _Float16* dst = (_Float16*)outp + (long)col * cout + o0;
                half4_t v;
#pragma unroll
                for (int j = 0; j < 4; ++j) v[j] = (_Float16)(acc[mf][nf][j] * inv[j] + add[j]);
                *(half4_t*)dst = v;
            } else {
                const int bb = col / NSP, sp = col - bb * NSP;
                float* dst = (float*)outp + ((long)bb * cout + o0) * NSP + sp;
#pragma unroll
                for (int j = 0; j < 4; ++j) dst[(long)j * NSP] = acc[mf][nf][j] * inv[j] + add[j];
            }
        }
    }
}

// ---- vall: per 128-col tile, prefix-sum x_t slices in f32 regs; per head MFMA with
//      W_h and write BN'd f16 into concat_t[col][head*128+o]. Same swizzled LDS scheme. ----
__global__ __launch_bounds__(256)
void vall_kernel(const _Float16* __restrict__ xt, const _Float16* __restrict__ vsw,
                 const float* __restrict__ vsbn, _Float16* __restrict__ concat_t)
{
    __shared__ _Float16 As[8192];
    __shared__ _Float16 Bs[8192];
    const int tid = threadIdx.x, lane = tid & 63;
    const int wv = tid >> 6, wm = wv >> 1, wn = wv & 1;
    const int colBase = blockIdx.x * 128;

    float bacc[4][8];
#pragma unroll
    for (int it = 0; it < 4; ++it)
#pragma unroll
        for (int j = 0; j < 8; ++j) bacc[it][j] = 0.f;

    for (int head = 0; head < NHEADS; ++head) {
        if (head) __syncthreads();
#pragma unroll
        for (int it = 0; it < 4; ++it) {
            const int c = it * 256 + tid;
            const int kg = c & 7, idx = c >> 3;
            const half8_t xv = *(const half8_t*)(xt + (long)(colBase + idx) * CDIM + head * 64 + kg * 8);
            half8_t bv;
#pragma unroll
            for (int j = 0; j < 8; ++j) { bacc[it][j] += (float)xv[j]; bv[j] = (_Float16)bacc[it][j]; }
            *(half8_t*)(Bs + (idx * 8 + (kg ^ (idx & 7))) * 8) = bv;   // swizzled slot
            const int skg = kg ^ (idx & 7);                            // inverse swizzle on source
            gload16(vsw + (long)head * (C4 * 64) + idx * 64 + skg * 8, As + c * 8);
        }
        __syncthreads();

        f32x4_t acc[4][4];
#pragma unroll
        for (int i = 0; i < 4; ++i)
#pragma unroll
            for (int j = 0; j < 4; ++j) acc[i][j] = (f32x4_t){0.f, 0.f, 0.f, 0.f};
#pragma unroll
        for (int ks = 0; ks < 2; ++ks) {
            const int kq = ks * 4 + (lane >> 4);
            half8_t a[4], b[4];
#pragma unroll
            for (int mf = 0; mf < 4; ++mf) {
                const int idx = wm * 64 + mf * 16 + (lane & 15);
                a[mf] = *(const half8_t*)(As + (idx * 8 + (kq ^ (idx & 7))) * 8);
            }
#pragma unroll
            for (int nf = 0; nf < 4; ++nf) {
                const int idx = wn * 64 + nf * 16 + (lane & 15);
                b[nf] = *(const half8_t*)(Bs + (idx * 8 + (kq ^ (idx & 7))) * 8);
            }
#pragma unroll
            for (int mf = 0; mf < 4; ++mf)
#pragma unroll
                for (int nf = 0; nf < 4; ++nf)
                    acc[mf][nf] = __builtin_amdgcn_mfma_f32_16x16x32_f16(a[mf], b[nf], acc[mf][nf], 0, 0, 0);
        }

        const int rbase = wm * 64 + (lane >> 4) * 4;
        const int cbase = colBase + wn * 64 + (lane & 15);
        const float* bnh = vsbn + head * 4 * C4;
#pragma unroll
        for (int mf = 0; mf < 4; ++mf) {
            const int o0 = rbase + mf * 16;
            float inv[4], add[4];
#pragma unroll
            for (int j = 0; j < 4; ++j) bn_coef(bnh, C4, o0 + j, inv[j], add[j]);
#pragma unroll
            for (int nf = 0; nf < 4; ++nf) {
                const int col = cbase + nf * 16;
                _Float16* dst = concat_t + (long)col * CCAT + head * C4 + o0;
                half4_t v;
#pragma unroll
                for (int j = 0; j < 4; ++j) v[j] = (_Float16)(acc[mf][nf][j] * inv[j] + add[j]);
                *(half4_t*)dst = v;
            }
        }
    }
}

// ---- depthwise 5x5 SAME + BN; feat_t [sp][256] (q = c<128) -> qdw_t [sp][128] ----
__global__ __launch_bounds__(256)
void dwconv_t_kernel(const _Float16* __restrict__ feat_t, const float* __restrict__ dww,
                     const float* __restrict__ dwbn, _Float16* __restrict__ qdw_t)
{
    const int h = blockIdx.x, b = blockIdx.y, ch0 = blockIdx.z * 64;
    __shared__ _Float16 rows[5][32][64];  // [dy][iw+2][c], borders zero
    for (int i = threadIdx.x; i < 5 * 32 * 64; i += 256) {
        const int dy = i / (32 * 64);
        const int rem = i - dy * (32 * 64);
        const int iw = rem >> 6, c = rem & 63;
        const int ih = h + dy - 2, w = iw - 2;
        _Float16 v = (_Float16)0.f;
        if (ih >= 0 && ih < 28 && w >= 0 && w < 28)
            v = feat_t[((long)b * NSP + ih * 28 + w) * CQK + ch0 + c];
        rows[dy][iw][c] = v;
    }
    const int pr = threadIdx.x & 31;
    const int c2 = pr * 2;
    float wr0[25], wr1[25];
#pragma unroll
    for (int q = 0; q < 25; ++q) {
        wr0[q] = dww[(ch0 + c2) * 25 + q];
        wr1[q] = dww[(ch0 + c2 + 1) * 25 + q];
    }
    float inv0, add0, inv1, add1;
    bn_coef(dwbn, C4, ch0 + c2, inv0, add0);
    bn_coef(dwbn, C4, ch0 + c2 + 1, inv1, add1);
    __syncthreads();
    for (int l = threadIdx.x; l < 28 * 32; l += 256) {
        const int w = l >> 5;
        float a0 = 0.f, a1 = 0.f;
#pragma unroll
        for (int dy = 0; dy < 5; ++dy)
#pragma unroll
            for (int dx = 0; dx < 5; ++dx) {
                const half2_t v2 = *(const half2_t*)(&rows[dy][w + dx][c2]);
                a0 += wr0[dy * 5 + dx] * (float)v2[0];
                a1 += wr1[dy * 5 + dx] * (float)v2[1];
            }
        half2_t o2; o2[0] = (_Float16)(a0 * inv0 + add0); o2[1] = (_Float16)(a1 * inv1 + add1);
        *(half2_t*)(qdw_t + ((long)b * NSP + h * 28 + w) * C4 + ch0 + c2) = o2;
    }
}

// ---- attention maps -> padded f16 [b][28 fix][32 q][32 k], zero-filled pads. ----
template<bool ROWMODE>
__global__ __launch_bounds__(256)
void attn_map_kernel(const _Float16* __restrict__ qdw_t, const _Float16* __restrict__ feat_t,
                     const float* __restrict__ biasv, _Float16* __restrict__ attn_out)
{
    const int fix = blockIdx.x, b = blockIdx.y;
    __shared__ _Float16 Qs[28][136];
    __shared__ _Float16 Ks[28][136];
    __shared__ float S[28][28];
    __shared__ float bsh[28];
    if (threadIdx.x < 28) bsh[threadIdx.x] = biasv[threadIdx.x];
    for (int l = threadIdx.x; l < 28 * 16; l += 256) {
        const int p = l >> 4, c8 = (l & 15) * 8;
        const int sp = ROWMODE ? (fix * 28 + p) : (p * 28 + fix);
        *(half8_t*)(&Qs[p][c8]) = *(const half8_t*)(qdw_t + ((long)b * NSP + sp) * C4 + c8);
        *(half8_t*)(&Ks[p][c8]) = *(const half8_t*)(feat_t + ((long)b * NSP + sp) * CQK + 128 + c8);
    }
    __syncthreads();
    for (int e = threadIdx.x; e < 784; e += 256) {
        const int qp = e / 28, kp = e - (e / 28) * 28;
        float acc = 0.f;
        const half2_t* qv = (const half2_t*)&Qs[qp][0];
        const half2_t* kv = (const half2_t*)&Ks[kp][0];
#pragma unroll
        for (int c = 0; c < 64; ++c) acc = fdot2(qv[c], kv[c], acc);
        const int dd = qp - kp;
        S[qp][kp] = acc * ATT_SCALE + bsh[dd < 0 ? -dd : dd];
    }
    __syncthreads();
    const int r = threadIdx.x >> 3, g = threadIdx.x & 7;
    if (r < 28) {
        float mx = -1e30f;
#pragma unroll
        for (int j = 0; j < 4; ++j) { const int k = g + j * 8; if (k < 28) mx = fmaxf(mx, S[r][k]); }
        mx = fmaxf(mx, __shfl_xor(mx, 1));
        mx = fmaxf(mx, __shfl_xor(mx, 2));
        mx = fmaxf(mx, __shfl_xor(mx, 4));
        float e4[4], sum = 0.f;
#pragma unroll
        for (int j = 0; j < 4; ++j) {
            const int k = g + j * 8;
            e4[j] = (k < 28) ? __expf(S[r][k] - mx) : 0.f;
            sum += e4[j];
        }
        sum += __shfl_xor(sum, 1);
        sum += __shfl_xor(sum, 2);
        sum += __shfl_xor(sum, 4);
        const float rinv = 1.f / sum;
#pragma unroll
        for (int j = 0; j < 4; ++j) { const int k = g + j * 8; if (k < 28) S[r][k] = e4[j] * rinv; }
    }
    __syncthreads();
    _Float16* dst = attn_out + ((long)b * 28 + fix) * 1024;
    for (int i = threadIdx.x; i < 1024; i += 256) {
        const int q = i >> 5, k = i & 31;
        dst[i] = (q < 28 && k < 28) ? (_Float16)S[q][k] : (_Float16)0.f;
    }
}

// ---- fused row+col attention apply + ReLU, in place on concat_t. ----
// Block = (dq of 32 channels, b), 512 threads / 8 waves.
__global__ __launch_bounds__(512)
void fused_stage_kernel(_Float16* __restrict__ concat_t,
                        const _Float16* __restrict__ attw,
                        const _Float16* __restrict__ atth)
{
    const int dq = blockIdx.x, b = blockIdx.y;
    __shared__ _Float16 V[32 * 904];
    __shared__ _Float16 M1[28 * 33 * 40];
    const int tid = threadIdx.x, lane = tid & 63, wv = tid >> 6;
    const int kg = lane >> 4, lr = lane & 15;

    _Float16* cbase = concat_t + (long)b * NSP * CCAT + dq * 32;

    // zero K-pads
    for (int p = tid; p < 32 * 28 * 4; p += 512) {
        const int d = p / 112, rem = p - d * 112;
        V[d * 904 + (rem >> 2) * 32 + 28 + (rem & 3)] = (_Float16)0.f;
    }
    for (int p = tid; p < 28 * 33 * 4; p += 512) {
        M1[(p >> 2) * 40 + 28 + (p & 3)] = (_Float16)0.f;
    }
    // load V chunk (transpose to d-major)
    for (int t = tid; t < 3136; t += 512) {
        const int sp = t >> 2, c0 = (t & 3) * 8;
        const int r = sp / 28, j = sp - r * 28;
        const half8_t v = *(const half8_t*)(cbase + (long)sp * CCAT + c0);
#pragma unroll
        for (int q = 0; q < 8; ++q) V[(c0 + q) * 904 + r * 32 + j] = v[q];
    }
    __syncthreads();

    // stage 1: rows r; D1[d][w] = sum_j V[d][r][j] * attw[b][r][w][j]
    for (int r = wv; r < 28; r += 8) {
        const _Float16* bw = attw + ((long)b * 28 + r) * 1024;
        half8_t a0 = *(const half8_t*)(V + lr * 904 + r * 32 + kg * 8);
        half8_t a1 = *(const half8_t*)(V + (16 + lr) * 904 + r * 32 + kg * 8);
        half8_t b0 = *(const half8_t*)(bw + lr * 32 + kg * 8);
        half8_t b1 = *(const half8_t*)(bw + (16 + lr) * 32 + kg * 8);
        f32x4_t acc[2][2];
#pragma unroll
        for (int i = 0; i < 2; ++i)
#pragma unroll
            for (int j = 0; j < 2; ++j) acc[i][j] = (f32x4_t){0.f, 0.f, 0.f, 0.f};
        acc[0][0] = __builtin_amdgcn_mfma_f32_16x16x32_f16(a0, b0, acc[0][0], 0, 0, 0);
        acc[0][1] = __builtin_amdgcn_mfma_f32_16x16x32_f16(a0, b1, acc[0][1], 0, 0, 0);
        acc[1][0] = __builtin_amdgcn_mfma_f32_16x16x32_f16(a1, b0, acc[1][0], 0, 0, 0);
        acc[1][1] = __builtin_amdgcn_mfma_f32_16x16x32_f16(a1, b1, acc[1][1], 0, 0, 0);
#pragma unroll
        for (int mt = 0; mt < 2; ++mt)
#pragma unroll
            for (int nt = 0; nt < 2; ++nt) {
                const int w = nt * 16 + lr;
                if (w < 28) {
                    const int dbase = mt * 16 + kg * 4;
#pragma unroll
                    for (int q = 0; q < 4; ++q)
                        M1[(w * 33 + dbase + q) * 40 + r] = (_Float16)acc[mt][nt][q];
                }
            }
    }
    __syncthreads();

    // stage 2: cols w; D2[d][h] = sum_k M1[w][d][k] * atth[b][w][h][k]; relu; write global
    for (int w = wv; w < 28; w += 8) {
        const _Float16* bh = atth + ((long)b * 28 + w) * 1024;
        half8_t a0 = *(const half8_t*)(M1 + (w * 33 + lr) * 40 + kg * 8);
        half8_t a1 = *(const half8_t*)(M1 + (w * 33 + 16 + lr) * 40 + kg * 8);
        half8_t b0 = *(const half8_t*)(bh + lr * 32 + kg * 8);
        half8_t b1 = *(const half8_t*)(bh + (16 + lr) * 32 + kg * 8);
        f32x4_t acc[2][2];
#pragma unroll
        for (int i = 0; i < 2; ++i)
#pragma unroll
            for (int j = 0; j < 2; ++j) acc[i][j] = (f32x4_t){0.f, 0.f, 0.f, 0.f};
        acc[0][0] = __builtin_amdgcn_mfma_f32_16x16x32_f16(a0, b0, acc[0][0], 0, 0, 0);
        acc[0][1] = __builtin_amdgcn_mfma_f32_16x16x32_f16(a0, b1, acc[0][1], 0, 0, 0);
        acc[1][0] = __builtin_amdgcn_mfma_f32_16x16x32_f16(a1, b0, acc[1][0], 0, 0, 0);
        acc[1][1] = __builtin_amdgcn_mfma_f32_16x16x32_f16(a1, b1, acc[1][1], 0, 0, 0);
#pragma unroll
        for (int mt = 0; mt < 2; ++mt)
#pragma unroll
            for (int nt = 0; nt < 2; ++nt) {
                const int hh = nt * 16 + lr;
                if (hh < 28) {
                    const int sp = hh * 28 + w;
                    half4_t v;
#pragma unroll
                    for (int q = 0; q < 4; ++q) v[q] = (_Float16)fmaxf(acc[mt][nt][q], 0.f);
                    *(half4_t*)(cbase + (long)sp * CCAT + mt * 16 + kg * 4) = v;
                }
            }
    }
}

extern "C" void kernel_launch(void* const* d_in, const int* in_sizes, int n_in,
                              void* d_out, int out_size, void* d_ws, size_t ws_size,
                              hipStream_t stream)
{
    const float* x        = (const float*)d_in[0];
    const float* qk_w     = (const float*)d_in[1];
    const float* qk_bn    = (const float*)d_in[2];
    const float* dws_w    = (const float*)d_in[3];
    const float* dws_bn   = (const float*)d_in[4];
    const float* vs_w     = (const float*)d_in[5];
    const float* vs_bn    = (const float*)d_in[6];
    const float* proj_w   = (const float*)d_in[7];
    const float* proj_bn  = (const float*)d_in[8];
    const float* bias_h   = (const float*)d_in[9];
    const float* bias_w   = (const float*)d_in[10];

    // --- scratch inside d_out (fully overwritten by proj GEMM at the end) ---
    char* ob = (char*)d_out;
    _Float16* x_t    = (_Float16*)ob;                    // 51,380,224 B
    _Float16* attw_p = (_Float16*)(ob + 51380224);       //  3,670,016 B
    _Float16* atth_p = (_Float16*)(ob + 55050240);       //  3,670,016 B -> 58,720,256
    _Float16* feat_t = (_Float16*)(ob + 58720256);       // 25,690,112 B -> 84,410,368
    _Float16* qdw_t  = (_Float16*)(ob + 84410368);       // 12,845,056 B -> 97,255,424

    // --- ws: concat_t + f16 weights ---
    _Float16* concat_t = (_Float16*)d_ws;                           // 102,760,448 B
    _Float16* w_h      = (_Float16*)((char*)d_ws + 102760448);      // 1,441,792 B
    _Float16* qk_w_h   = w_h;
    _Float16* vs_w_h   = w_h + 131072;
    _Float16* proj_w_h = w_h + 196608;

    transpose_x_kernel<<<dim3(16, NB), 256, 0, stream>>>(x, x_t);
    convert_w_kernel<<<704, 256, 0, stream>>>(qk_w, vs_w, proj_w, w_h);

    // feat_t = BN(qk_w @ x)   [sp][256] f16
    mfma_gemm_kernel<CDIM, 2, true><<<784, 256, 0, stream>>>(
        x_t, qk_w_h, qk_bn, feat_t, CQK);
    dwconv_t_kernel<<<dim3(28, NB, 2), 256, 0, stream>>>(feat_t, dws_w, dws_bn, qdw_t);
    attn_map_kernel<true><<<dim3(28, NB), 256, 0, stream>>>(qdw_t, feat_t, bias_w, attw_p);
    attn_map_kernel<false><<<dim3(28, NB), 256, 0, stream>>>(qdw_t, feat_t, bias_h, atth_p);

    // all-heads V GEMM with on-the-fly prefix-summed cascade input
    vall_kernel<<<392, 256, 0, stream>>>(x_t, vs_w_h, vs_bn, concat_t);

    // fused row+col attention apply + relu, in place on concat_t
    fused_stage_kernel<<<dim3(32, NB), 512, 0, stream>>>(concat_t, attw_p, atth_p);

    // out = BN(proj_w @ relu(concat))
    mfma_gemm_kernel<CCAT, 4, false><<<1568, 256, 0, stream>>>(
        concat_t, proj_w_h, proj_bn, (float*)d_out, CDIM);
}